// Round 1
// baseline (904.343 us; speedup 1.0000x reference)
//
#include <hip/hip_runtime.h>
#include <math.h>

#define N_NODES 100000
#define DIM 64
#define N_EDGES 1250000

// ---------------------------------------------------------------------------
// deg[i] = #edges with row == i
__global__ void deg_kernel(const int* __restrict__ row, int* __restrict__ deg, int E) {
    int tid = blockIdx.x * blockDim.x + threadIdx.x;
    int stride = gridDim.x * blockDim.x;
    for (int e = tid; e < E; e += stride) {
        atomicAdd(&deg[row[e]], 1);
    }
}

// dis[i] = deg>0 ? deg^-0.5 : 0
__global__ void dis_kernel(const int* __restrict__ deg, float* __restrict__ dis, int N) {
    int i = blockIdx.x * blockDim.x + threadIdx.x;
    if (i < N) {
        int d = deg[i];
        dis[i] = (d > 0) ? (float)(1.0 / sqrt((double)d)) : 0.0f;
    }
}

// One wave per edge; lane = embedding dim. Coalesced 256B gather of
// x_old[col], 64 scalar f32 atomicAdds into x_new[row].
__global__ void scatter_kernel(const int* __restrict__ row, const int* __restrict__ col,
                               const float* __restrict__ x_old, float* __restrict__ x_new,
                               int E) {
    int lane = threadIdx.x & 63;
    int wave = (blockIdx.x * blockDim.x + threadIdx.x) >> 6;
    int nwaves = (gridDim.x * blockDim.x) >> 6;
    for (int e = wave; e < E; e += nwaves) {
        int r = row[e];
        int c = col[e];
        float v = x_old[(size_t)c * DIM + lane];
        atomicAdd(&x_new[(size_t)r * DIM + lane], v);
    }
}

// x *= dis[i]^2 (store back unless last layer); acc += x; last layer: acc *= 0.25
// MODE 0: acc = base + v (first layer, base = emb, acc uninitialized)
// MODE 1: acc += v, store x back
// MODE 2: acc = (acc + v) * 0.25, no store-back
template <int MODE>
__global__ void finalize_kernel(float* __restrict__ x, const float* __restrict__ dis,
                                const float* __restrict__ base, float* __restrict__ acc,
                                int N) {
    int idx = blockIdx.x * blockDim.x + threadIdx.x;  // over N * DIM/4 float4s
    if (idx < N * (DIM / 4)) {
        int i = idx >> 4;  // node index (16 float4s per node)
        float s = dis[i];
        float s2 = s * s;
        float4 v = reinterpret_cast<float4*>(x)[idx];
        v.x *= s2; v.y *= s2; v.z *= s2; v.w *= s2;
        if (MODE != 2) {
            reinterpret_cast<float4*>(x)[idx] = v;
        }
        float4 a;
        if (MODE == 0) {
            a = reinterpret_cast<const float4*>(base)[idx];
        } else {
            a = reinterpret_cast<float4*>(acc)[idx];
        }
        a.x += v.x; a.y += v.y; a.z += v.z; a.w += v.w;
        if (MODE == 2) {
            a.x *= 0.25f; a.y *= 0.25f; a.z *= 0.25f; a.w *= 0.25f;
        }
        reinterpret_cast<float4*>(acc)[idx] = a;
    }
}

extern "C" void kernel_launch(void* const* d_in, const int* in_sizes, int n_in,
                              void* d_out, int out_size, void* d_ws, size_t ws_size,
                              hipStream_t stream) {
    const int* edge = (const int*)d_in[0];       // (2, E) int32
    const int* row = edge;
    const int* col = edge + N_EDGES;
    const float* emb = (const float*)d_in[1];    // (N, 64) f32
    float* out = (float*)d_out;                  // (N, 64) f32 = acc

    // Workspace layout (256B-aligned chunks):
    //   deg  : N int32            (0.4 MB)
    //   dis  : N f32              (0.4 MB)
    //   bufA : N*64 f32           (25.6 MB)
    //   bufB : N*64 f32           (25.6 MB)
    char* ws = (char*)d_ws;
    size_t off = 0;
    auto alloc = [&](size_t bytes) {
        char* p = ws + off;
        off += (bytes + 255) & ~(size_t)255;
        return p;
    };
    int*   deg  = (int*)alloc((size_t)N_NODES * sizeof(int));
    float* dis  = (float*)alloc((size_t)N_NODES * sizeof(float));
    float* bufA = (float*)alloc((size_t)N_NODES * DIM * sizeof(float));
    float* bufB = (float*)alloc((size_t)N_NODES * DIM * sizeof(float));

    const size_t XBYTES = (size_t)N_NODES * DIM * sizeof(float);
    const int fin_blocks = (N_NODES * (DIM / 4) + 255) / 256;

    // degree + normalization (once; depends only on row)
    hipMemsetAsync(deg, 0, (size_t)N_NODES * sizeof(int), stream);
    deg_kernel<<<2048, 256, 0, stream>>>(row, deg, N_EDGES);
    dis_kernel<<<(N_NODES + 255) / 256, 256, 0, stream>>>(deg, dis, N_NODES);

    // ---- layer 1: emb -> bufA; out = emb + bufA*dis^2
    hipMemsetAsync(bufA, 0, XBYTES, stream);
    scatter_kernel<<<4096, 256, 0, stream>>>(row, col, emb, bufA, N_EDGES);
    finalize_kernel<0><<<fin_blocks, 256, 0, stream>>>(bufA, dis, emb, out, N_NODES);

    // ---- layer 2: bufA -> bufB; out += bufB*dis^2
    hipMemsetAsync(bufB, 0, XBYTES, stream);
    scatter_kernel<<<4096, 256, 0, stream>>>(row, col, bufA, bufB, N_EDGES);
    finalize_kernel<1><<<fin_blocks, 256, 0, stream>>>(bufB, dis, nullptr, out, N_NODES);

    // ---- layer 3: bufB -> bufA; out = (out + bufA*dis^2) * 0.25
    hipMemsetAsync(bufA, 0, XBYTES, stream);
    scatter_kernel<<<4096, 256, 0, stream>>>(row, col, bufB, bufA, N_EDGES);
    finalize_kernel<2><<<fin_blocks, 256, 0, stream>>>(bufA, dis, nullptr, out, N_NODES);
}

// Round 2
// 586.155 us; speedup vs baseline: 1.5428x; 1.5428x over previous
//
#include <hip/hip_runtime.h>
#include <math.h>

#define N_NODES 100000
#define DIM 64
#define N_EDGES 1250000
#define SCAN_THREADS 1024

// ---------------------------------------------------------------------------
// deg[i] = #edges with row == i  (int histogram; only 1.25M small atomics)
__global__ void deg_kernel(const int* __restrict__ row, int* __restrict__ deg, int E) {
    int tid = blockIdx.x * blockDim.x + threadIdx.x;
    int stride = gridDim.x * blockDim.x;
    for (int e = tid; e < E; e += stride) {
        atomicAdd(&deg[row[e]], 1);
    }
}

// Single-block exclusive scan: deg[N] -> row_ptr[N+1]; also emits cursor copy
// (cursor may alias deg: deg[i] is read before the aliased write) and
// dis[i] = deg>0 ? deg^-0.5 : 0.
__global__ void __launch_bounds__(SCAN_THREADS) scan_kernel(
        const int* __restrict__ deg, int* __restrict__ row_ptr,
        int* __restrict__ cursor, float* __restrict__ dis, int N) {
    __shared__ int partial[SCAN_THREADS];
    int t = threadIdx.x;
    int seg = (N + SCAN_THREADS - 1) / SCAN_THREADS;
    int lo = t * seg;
    int hi = min(lo + seg, N);
    int s = 0;
    for (int i = lo; i < hi; ++i) s += deg[i];
    partial[t] = s;
    __syncthreads();
    // Hillis-Steele inclusive scan over 1024 partials
    for (int off = 1; off < SCAN_THREADS; off <<= 1) {
        int v = (t >= off) ? partial[t - off] : 0;
        __syncthreads();
        partial[t] += v;
        __syncthreads();
    }
    int base = (t > 0) ? partial[t - 1] : 0;
    for (int i = lo; i < hi; ++i) {
        int d = deg[i];                 // read BEFORE aliased cursor write
        row_ptr[i] = base;
        cursor[i] = base;
        dis[i] = (d > 0) ? (float)(1.0 / sqrt((double)d)) : 0.0f;
        base += d;
    }
    if (t == SCAN_THREADS - 1) row_ptr[N] = base;
}

// Bucket edges: csr_col[row_ptr[r] .. ] = all cols with row==r.
__global__ void fill_kernel(const int* __restrict__ row, const int* __restrict__ col,
                            int* __restrict__ cursor, int* __restrict__ csr_col, int E) {
    int tid = blockIdx.x * blockDim.x + threadIdx.x;
    int stride = gridDim.x * blockDim.x;
    for (int e = tid; e < E; e += stride) {
        int pos = atomicAdd(&cursor[row[e]], 1);
        csr_col[pos] = col[e];
    }
}

// One wave per node. Lanes split into 4 groups of 16; group g handles edges
// start+g, start+g+4, ... Each lane loads float4 (16B) -> one wave iteration
// gathers 4 full 256B rows in one coalesced load. Cross-group reduction via
// shfl_xor(16/32). Fused epilogue: x_new = acc*dis^2 (except last layer) and
// the running `out` accumulation — wave owns the row, so zero atomics.
// MODE 0: out = base + v          (layer 1, base = emb)
// MODE 1: out += v                (layer 2)
// MODE 2: out = (out + v) * 0.25  (layer 3, no x_new store)
template <int MODE>
__global__ void gather_kernel(const int* __restrict__ row_ptr, const int* __restrict__ csr_col,
                              const float* __restrict__ dis,
                              const float* __restrict__ x_old, float* __restrict__ x_new,
                              const float* __restrict__ base, float* __restrict__ out, int N) {
    int wid = (int)((blockIdx.x * (size_t)blockDim.x + threadIdx.x) >> 6);
    if (wid >= N) return;
    int lane = threadIdx.x & 63;
    int g = lane >> 4;   // edge-group 0..3
    int l = lane & 15;   // lane within group: owns dims 4l..4l+3

    int start = row_ptr[wid];
    int end = row_ptr[wid + 1];

    float4 acc0 = make_float4(0.f, 0.f, 0.f, 0.f);
    float4 acc1 = make_float4(0.f, 0.f, 0.f, 0.f);
    int e = start + g;
    // unroll-by-2 per group: 8 edges per wave iteration, 2 outstanding loads
    for (; e + 4 < end; e += 8) {
        int c0 = csr_col[e];
        int c1 = csr_col[e + 4];
        float4 v0 = *reinterpret_cast<const float4*>(&x_old[(size_t)c0 * DIM + l * 4]);
        float4 v1 = *reinterpret_cast<const float4*>(&x_old[(size_t)c1 * DIM + l * 4]);
        acc0.x += v0.x; acc0.y += v0.y; acc0.z += v0.z; acc0.w += v0.w;
        acc1.x += v1.x; acc1.y += v1.y; acc1.z += v1.z; acc1.w += v1.w;
    }
    if (e < end) {
        int c0 = csr_col[e];
        float4 v0 = *reinterpret_cast<const float4*>(&x_old[(size_t)c0 * DIM + l * 4]);
        acc0.x += v0.x; acc0.y += v0.y; acc0.z += v0.z; acc0.w += v0.w;
    }
    acc0.x += acc1.x; acc0.y += acc1.y; acc0.z += acc1.z; acc0.w += acc1.w;

    // sum the 4 groups (lanes l, l+16, l+32, l+48 hold the same dims)
    #pragma unroll
    for (int off = 16; off <= 32; off <<= 1) {
        acc0.x += __shfl_xor(acc0.x, off, 64);
        acc0.y += __shfl_xor(acc0.y, off, 64);
        acc0.z += __shfl_xor(acc0.z, off, 64);
        acc0.w += __shfl_xor(acc0.w, off, 64);
    }

    if (g == 0) {
        float s = dis[wid];
        float s2 = s * s;
        acc0.x *= s2; acc0.y *= s2; acc0.z *= s2; acc0.w *= s2;
        size_t o = (size_t)wid * DIM + l * 4;
        if (MODE != 2) {
            *reinterpret_cast<float4*>(&x_new[o]) = acc0;
        }
        float4 a;
        if (MODE == 0) {
            a = *reinterpret_cast<const float4*>(&base[o]);
        } else {
            a = *reinterpret_cast<const float4*>(&out[o]);
        }
        a.x += acc0.x; a.y += acc0.y; a.z += acc0.z; a.w += acc0.w;
        if (MODE == 2) {
            a.x *= 0.25f; a.y *= 0.25f; a.z *= 0.25f; a.w *= 0.25f;
        }
        *reinterpret_cast<float4*>(&out[o]) = a;
    }
}

extern "C" void kernel_launch(void* const* d_in, const int* in_sizes, int n_in,
                              void* d_out, int out_size, void* d_ws, size_t ws_size,
                              hipStream_t stream) {
    const int* edge = (const int*)d_in[0];       // (2, E) int32
    const int* row = edge;
    const int* col = edge + N_EDGES;
    const float* emb = (const float*)d_in[1];    // (N, 64) f32
    float* out = (float*)d_out;                  // (N, 64) f32

    // Workspace layout:
    //   deg/cursor : N int32    (0.4 MB)  -- cursor aliases deg after scan
    //   row_ptr    : N+1 int32  (0.4 MB)
    //   dis        : N f32      (0.4 MB)
    //   csr_col    : E int32    (5.0 MB)
    //   bufA       : N*64 f32   (25.6 MB)
    //   bufB       : N*64 f32   (25.6 MB)
    char* ws = (char*)d_ws;
    size_t off = 0;
    auto alloc = [&](size_t bytes) {
        char* p = ws + off;
        off += (bytes + 255) & ~(size_t)255;
        return p;
    };
    int*   deg     = (int*)alloc((size_t)N_NODES * sizeof(int));
    int*   cursor  = deg;  // aliased: deg dead after scan_kernel
    int*   row_ptr = (int*)alloc(((size_t)N_NODES + 1) * sizeof(int));
    float* dis     = (float*)alloc((size_t)N_NODES * sizeof(float));
    int*   csr_col = (int*)alloc((size_t)N_EDGES * sizeof(int));
    float* bufA    = (float*)alloc((size_t)N_NODES * DIM * sizeof(float));
    float* bufB    = (float*)alloc((size_t)N_NODES * DIM * sizeof(float));

    const int gather_blocks = (N_NODES * 64 + 255) / 256;  // one wave per node

    // CSR build (per call — kernel_launch must recompute everything)
    hipMemsetAsync(deg, 0, (size_t)N_NODES * sizeof(int), stream);
    deg_kernel<<<2048, 256, 0, stream>>>(row, deg, N_EDGES);
    scan_kernel<<<1, SCAN_THREADS, 0, stream>>>(deg, row_ptr, cursor, dis, N_NODES);
    fill_kernel<<<2048, 256, 0, stream>>>(row, col, cursor, csr_col, N_EDGES);

    // 3 fused propagate+accumulate layers (no atomics, no big memsets)
    gather_kernel<0><<<gather_blocks, 256, 0, stream>>>(row_ptr, csr_col, dis, emb, bufA, emb, out, N_NODES);
    gather_kernel<1><<<gather_blocks, 256, 0, stream>>>(row_ptr, csr_col, dis, bufA, bufB, nullptr, out, N_NODES);
    gather_kernel<2><<<gather_blocks, 256, 0, stream>>>(row_ptr, csr_col, dis, bufB, nullptr, nullptr, out, N_NODES);
}

// Round 3
// 326.709 us; speedup vs baseline: 2.7680x; 1.7941x over previous
//
#include <hip/hip_runtime.h>
#include <math.h>

#define N_NODES 100000
#define DIM 64
#define N_EDGES 1250000
#define SCAN_BLOCKS 256

// ---------------------------------------------------------------------------
// deg[i] = #edges with row == i  (int histogram; only 1.25M small atomics)
__global__ void deg_kernel(const int* __restrict__ row, int* __restrict__ deg, int E) {
    int tid = blockIdx.x * blockDim.x + threadIdx.x;
    int stride = gridDim.x * blockDim.x;
    for (int e = tid; e < E; e += stride) {
        atomicAdd(&deg[row[e]], 1);
    }
}

// ---- 3-kernel device-wide exclusive scan of deg ---------------------------
// (1) per-chunk partial sums (coalesced strided reads within chunk)
__global__ void partial_kernel(const int* __restrict__ deg, int* __restrict__ blocksum,
                               int N, int chunk) {
    __shared__ int sh[256];
    int b = blockIdx.x;
    int lo = b * chunk, hi = min(lo + chunk, N);
    int s = 0;
    for (int i = lo + (int)threadIdx.x; i < hi; i += 256) s += deg[i];
    sh[threadIdx.x] = s;
    __syncthreads();
    for (int off = 128; off > 0; off >>= 1) {
        if ((int)threadIdx.x < off) sh[threadIdx.x] += sh[threadIdx.x + off];
        __syncthreads();
    }
    if (threadIdx.x == 0) blocksum[b] = sh[0];
}

// (2) single tiny block: exclusive-scan the SCAN_BLOCKS partials in place;
//     also writes row_ptr[N] = total edge count.
__global__ void scan_small_kernel(int* __restrict__ blocksum, int* __restrict__ row_ptr, int N) {
    __shared__ int sh[SCAN_BLOCKS];
    int t = threadIdx.x;
    int v = blocksum[t];
    sh[t] = v;
    __syncthreads();
    for (int off = 1; off < SCAN_BLOCKS; off <<= 1) {
        int u = (t >= off) ? sh[t - off] : 0;
        __syncthreads();
        sh[t] += u;
        __syncthreads();
    }
    blocksum[t] = sh[t] - v;  // exclusive = inclusive - own
    if (t == SCAN_BLOCKS - 1) row_ptr[N] = sh[SCAN_BLOCKS - 1];
}

// (3) re-read deg, per-tile LDS scan + block offset; emit row_ptr/cursor/dis.
//     cursor may alias deg (each element read into a register before write).
__global__ void emit_kernel(const int* __restrict__ deg, const int* __restrict__ blocksum,
                            int* __restrict__ row_ptr, int* __restrict__ cursor,
                            float* __restrict__ dis, int N, int chunk) {
    __shared__ int sh[256];
    int b = blockIdx.x;
    int t = threadIdx.x;
    int lo = b * chunk, hi = min(lo + chunk, N);
    int running = blocksum[b];
    for (int base = lo; base < hi; base += 256) {
        int i = base + t;
        int d = (i < hi) ? deg[i] : 0;
        sh[t] = d;
        __syncthreads();
        for (int off = 1; off < 256; off <<= 1) {
            int u = (t >= off) ? sh[t - off] : 0;
            __syncthreads();
            sh[t] += u;
            __syncthreads();
        }
        int exc = sh[t] - d;
        if (i < hi) {
            int rp = running + exc;
            row_ptr[i] = rp;
            cursor[i] = rp;
            dis[i] = (d > 0) ? (float)(1.0 / sqrt((double)d)) : 0.0f;
        }
        running += sh[255];
        __syncthreads();  // protect sh before next tile overwrites it
    }
}

// Bucket edges: csr_col[row_ptr[r] .. ] = all cols with row==r.
__global__ void fill_kernel(const int* __restrict__ row, const int* __restrict__ col,
                            int* __restrict__ cursor, int* __restrict__ csr_col, int E) {
    int tid = blockIdx.x * blockDim.x + threadIdx.x;
    int stride = gridDim.x * blockDim.x;
    for (int e = tid; e < E; e += stride) {
        int pos = atomicAdd(&cursor[row[e]], 1);
        csr_col[pos] = col[e];
    }
}

// One wave per node. Lanes split into 4 groups of 16; group g handles edges
// start+g, start+g+4, ... Each lane loads float4 (16B) -> one wave iteration
// gathers 4 full 256B rows in one coalesced load. Cross-group reduction via
// shfl_xor(16/32). Fused epilogue: x_new = acc*dis^2 (except last layer) and
// the running `out` accumulation — wave owns the row, so zero atomics.
// MODE 0: out = base + v          (layer 1, base = emb)
// MODE 1: out += v                (layer 2)
// MODE 2: out = (out + v) * 0.25  (layer 3, no x_new store)
template <int MODE>
__global__ void gather_kernel(const int* __restrict__ row_ptr, const int* __restrict__ csr_col,
                              const float* __restrict__ dis,
                              const float* __restrict__ x_old, float* __restrict__ x_new,
                              const float* __restrict__ base, float* __restrict__ out, int N) {
    int wid = (int)((blockIdx.x * (size_t)blockDim.x + threadIdx.x) >> 6);
    if (wid >= N) return;
    int lane = threadIdx.x & 63;
    int g = lane >> 4;   // edge-group 0..3
    int l = lane & 15;   // lane within group: owns dims 4l..4l+3

    int start = row_ptr[wid];
    int end = row_ptr[wid + 1];

    float4 acc0 = make_float4(0.f, 0.f, 0.f, 0.f);
    float4 acc1 = make_float4(0.f, 0.f, 0.f, 0.f);
    int e = start + g;
    // unroll-by-2 per group: 8 edges per wave iteration, 2 outstanding loads
    for (; e + 4 < end; e += 8) {
        int c0 = csr_col[e];
        int c1 = csr_col[e + 4];
        float4 v0 = *reinterpret_cast<const float4*>(&x_old[(size_t)c0 * DIM + l * 4]);
        float4 v1 = *reinterpret_cast<const float4*>(&x_old[(size_t)c1 * DIM + l * 4]);
        acc0.x += v0.x; acc0.y += v0.y; acc0.z += v0.z; acc0.w += v0.w;
        acc1.x += v1.x; acc1.y += v1.y; acc1.z += v1.z; acc1.w += v1.w;
    }
    if (e < end) {
        int c0 = csr_col[e];
        float4 v0 = *reinterpret_cast<const float4*>(&x_old[(size_t)c0 * DIM + l * 4]);
        acc0.x += v0.x; acc0.y += v0.y; acc0.z += v0.z; acc0.w += v0.w;
    }
    acc0.x += acc1.x; acc0.y += acc1.y; acc0.z += acc1.z; acc0.w += acc1.w;

    // sum the 4 groups (lanes l, l+16, l+32, l+48 hold the same dims)
    #pragma unroll
    for (int off = 16; off <= 32; off <<= 1) {
        acc0.x += __shfl_xor(acc0.x, off, 64);
        acc0.y += __shfl_xor(acc0.y, off, 64);
        acc0.z += __shfl_xor(acc0.z, off, 64);
        acc0.w += __shfl_xor(acc0.w, off, 64);
    }

    if (g == 0) {
        float s = dis[wid];
        float s2 = s * s;
        acc0.x *= s2; acc0.y *= s2; acc0.z *= s2; acc0.w *= s2;
        size_t o = (size_t)wid * DIM + l * 4;
        if (MODE != 2) {
            *reinterpret_cast<float4*>(&x_new[o]) = acc0;
        }
        float4 a;
        if (MODE == 0) {
            a = *reinterpret_cast<const float4*>(&base[o]);
        } else {
            a = *reinterpret_cast<const float4*>(&out[o]);
        }
        a.x += acc0.x; a.y += acc0.y; a.z += acc0.z; a.w += acc0.w;
        if (MODE == 2) {
            a.x *= 0.25f; a.y *= 0.25f; a.z *= 0.25f; a.w *= 0.25f;
        }
        *reinterpret_cast<float4*>(&out[o]) = a;
    }
}

extern "C" void kernel_launch(void* const* d_in, const int* in_sizes, int n_in,
                              void* d_out, int out_size, void* d_ws, size_t ws_size,
                              hipStream_t stream) {
    const int* edge = (const int*)d_in[0];       // (2, E) int32
    const int* row = edge;
    const int* col = edge + N_EDGES;
    const float* emb = (const float*)d_in[1];    // (N, 64) f32
    float* out = (float*)d_out;                  // (N, 64) f32

    // Workspace layout:
    //   deg/cursor : N int32          (0.4 MB)  -- cursor aliases deg
    //   row_ptr    : N+1 int32        (0.4 MB)
    //   dis        : N f32            (0.4 MB)
    //   blocksum   : SCAN_BLOCKS int  (1 KB)
    //   csr_col    : E int32          (5.0 MB)
    //   bufA       : N*64 f32         (25.6 MB)
    //   bufB       : N*64 f32         (25.6 MB)
    char* ws = (char*)d_ws;
    size_t off = 0;
    auto alloc = [&](size_t bytes) {
        char* p = ws + off;
        off += (bytes + 255) & ~(size_t)255;
        return p;
    };
    int*   deg      = (int*)alloc((size_t)N_NODES * sizeof(int));
    int*   cursor   = deg;  // aliased: deg dead after emit_kernel
    int*   row_ptr  = (int*)alloc(((size_t)N_NODES + 1) * sizeof(int));
    float* dis      = (float*)alloc((size_t)N_NODES * sizeof(float));
    int*   blocksum = (int*)alloc((size_t)SCAN_BLOCKS * sizeof(int));
    int*   csr_col  = (int*)alloc((size_t)N_EDGES * sizeof(int));
    float* bufA     = (float*)alloc((size_t)N_NODES * DIM * sizeof(float));
    float* bufB     = (float*)alloc((size_t)N_NODES * DIM * sizeof(float));

    const int gather_blocks = (N_NODES * 64 + 255) / 256;  // one wave per node
    const int chunk = (N_NODES + SCAN_BLOCKS - 1) / SCAN_BLOCKS;

    // CSR build (per call — kernel_launch must recompute everything)
    hipMemsetAsync(deg, 0, (size_t)N_NODES * sizeof(int), stream);
    deg_kernel<<<2048, 256, 0, stream>>>(row, deg, N_EDGES);
    partial_kernel<<<SCAN_BLOCKS, 256, 0, stream>>>(deg, blocksum, N_NODES, chunk);
    scan_small_kernel<<<1, SCAN_BLOCKS, 0, stream>>>(blocksum, row_ptr, N_NODES);
    emit_kernel<<<SCAN_BLOCKS, 256, 0, stream>>>(deg, blocksum, row_ptr, cursor, dis,
                                                 N_NODES, chunk);
    fill_kernel<<<2048, 256, 0, stream>>>(row, col, cursor, csr_col, N_EDGES);

    // 3 fused propagate+accumulate layers (no atomics, no big memsets)
    gather_kernel<0><<<gather_blocks, 256, 0, stream>>>(row_ptr, csr_col, dis, emb, bufA, emb, out, N_NODES);
    gather_kernel<1><<<gather_blocks, 256, 0, stream>>>(row_ptr, csr_col, dis, bufA, bufB, nullptr, out, N_NODES);
    gather_kernel<2><<<gather_blocks, 256, 0, stream>>>(row_ptr, csr_col, dis, bufB, nullptr, nullptr, out, N_NODES);
}

// Round 4
// 286.873 us; speedup vs baseline: 3.1524x; 1.1389x over previous
//
#include <hip/hip_runtime.h>
#include <math.h>

#define N_NODES 100000
#define DIM 64
#define N_EDGES 1250000
#define SCAN_BLOCKS 256
#define NRANGE 8
#define RANGE_ROWS ((N_NODES + NRANGE - 1) / NRANGE)   // 12500 rows per XCD-range

// ---------------------------------------------------------------------------
// deg[i] = #edges with row == i  (int histogram)
__global__ void deg_kernel(const int* __restrict__ row, int* __restrict__ deg, int E) {
    int tid = blockIdx.x * blockDim.x + threadIdx.x;
    int stride = gridDim.x * blockDim.x;
    for (int e = tid; e < E; e += stride) {
        atomicAdd(&deg[row[e]], 1);
    }
}

// ---- 3-kernel device-wide exclusive scan of deg ---------------------------
__global__ void partial_kernel(const int* __restrict__ deg, int* __restrict__ blocksum,
                               int N, int chunk) {
    __shared__ int sh[256];
    int b = blockIdx.x;
    int lo = b * chunk, hi = min(lo + chunk, N);
    int s = 0;
    for (int i = lo + (int)threadIdx.x; i < hi; i += 256) s += deg[i];
    sh[threadIdx.x] = s;
    __syncthreads();
    for (int off = 128; off > 0; off >>= 1) {
        if ((int)threadIdx.x < off) sh[threadIdx.x] += sh[threadIdx.x + off];
        __syncthreads();
    }
    if (threadIdx.x == 0) blocksum[b] = sh[0];
}

__global__ void scan_small_kernel(int* __restrict__ blocksum, int* __restrict__ row_ptr, int N) {
    __shared__ int sh[SCAN_BLOCKS];
    int t = threadIdx.x;
    int v = blocksum[t];
    sh[t] = v;
    __syncthreads();
    for (int off = 1; off < SCAN_BLOCKS; off <<= 1) {
        int u = (t >= off) ? sh[t - off] : 0;
        __syncthreads();
        sh[t] += u;
        __syncthreads();
    }
    blocksum[t] = sh[t] - v;  // exclusive = inclusive - own
    if (t == SCAN_BLOCKS - 1) row_ptr[N] = sh[SCAN_BLOCKS - 1];
}

__global__ void emit_kernel(const int* __restrict__ deg, const int* __restrict__ blocksum,
                            int* __restrict__ row_ptr, int* __restrict__ cursor,
                            float* __restrict__ dis, int N, int chunk) {
    __shared__ int sh[256];
    int b = blockIdx.x;
    int t = threadIdx.x;
    int lo = b * chunk, hi = min(lo + chunk, N);
    int running = blocksum[b];
    for (int base = lo; base < hi; base += 256) {
        int i = base + t;
        int d = (i < hi) ? deg[i] : 0;
        sh[t] = d;
        __syncthreads();
        for (int off = 1; off < 256; off <<= 1) {
            int u = (t >= off) ? sh[t - off] : 0;
            __syncthreads();
            sh[t] += u;
            __syncthreads();
        }
        int exc = sh[t] - d;
        if (i < hi) {
            int rp = running + exc;
            row_ptr[i] = rp;
            cursor[i] = rp;
            dis[i] = (d > 0) ? (float)(1.0 / sqrt((double)d)) : 0.0f;
        }
        running += sh[255];
        __syncthreads();
    }
}

// XCD-partitioned CSR fill. Cohort r = blocks with blockIdx&7==r (dispatch
// round-robins blocks across the 8 XCDs, so a cohort stays on one XCD).
// Cohort r only processes edges whose row is in range r -> every store to a
// given csr_col cache line comes from ONE XCD's L2, killing the 17x
// partial-line write amplification seen in round 3 (87MB for a 5MB payload).
// Cost: row[] is read by all 8 cohorts (8 x 5MB, L3-resident -> cheap).
__global__ void fill_kernel(const int* __restrict__ row, const int* __restrict__ col,
                            int* __restrict__ cursor, int* __restrict__ csr_col, int E) {
    int rng = blockIdx.x & (NRANGE - 1);
    int cb = blockIdx.x >> 3;                        // block id within cohort
    int cohort_threads = ((int)gridDim.x >> 3) * blockDim.x;
    int tid = cb * blockDim.x + threadIdx.x;
    int lo = rng * RANGE_ROWS;
    for (int e = tid; e < E; e += cohort_threads) {
        int r = row[e];
        if ((unsigned)(r - lo) < (unsigned)RANGE_ROWS) {
            int pos = atomicAdd(&cursor[r], 1);
            csr_col[pos] = col[e];
        }
    }
}

// One wave per node; 4 groups of 16 lanes, each group loads one 256B row as
// 16 x float4; cross-group reduce via shfl_xor. Fused scale + accumulation.
// MODE 0: out = base + v          (layer 1, base = emb)
// MODE 1: out += v                (layer 2)
// MODE 2: out = (out + v) * 0.25  (layer 3, no x_new store)
template <int MODE>
__global__ void gather_kernel(const int* __restrict__ row_ptr, const int* __restrict__ csr_col,
                              const float* __restrict__ dis,
                              const float* __restrict__ x_old, float* __restrict__ x_new,
                              const float* __restrict__ base, float* __restrict__ out, int N) {
    int wid = (int)((blockIdx.x * (size_t)blockDim.x + threadIdx.x) >> 6);
    if (wid >= N) return;
    int lane = threadIdx.x & 63;
    int g = lane >> 4;   // edge-group 0..3
    int l = lane & 15;   // lane within group: owns dims 4l..4l+3

    int start = row_ptr[wid];
    int end = row_ptr[wid + 1];

    float4 acc0 = make_float4(0.f, 0.f, 0.f, 0.f);
    float4 acc1 = make_float4(0.f, 0.f, 0.f, 0.f);
    int e = start + g;
    for (; e + 4 < end; e += 8) {
        int c0 = csr_col[e];
        int c1 = csr_col[e + 4];
        float4 v0 = *reinterpret_cast<const float4*>(&x_old[(size_t)c0 * DIM + l * 4]);
        float4 v1 = *reinterpret_cast<const float4*>(&x_old[(size_t)c1 * DIM + l * 4]);
        acc0.x += v0.x; acc0.y += v0.y; acc0.z += v0.z; acc0.w += v0.w;
        acc1.x += v1.x; acc1.y += v1.y; acc1.z += v1.z; acc1.w += v1.w;
    }
    if (e < end) {
        int c0 = csr_col[e];
        float4 v0 = *reinterpret_cast<const float4*>(&x_old[(size_t)c0 * DIM + l * 4]);
        acc0.x += v0.x; acc0.y += v0.y; acc0.z += v0.z; acc0.w += v0.w;
    }
    acc0.x += acc1.x; acc0.y += acc1.y; acc0.z += acc1.z; acc0.w += acc1.w;

    #pragma unroll
    for (int off = 16; off <= 32; off <<= 1) {
        acc0.x += __shfl_xor(acc0.x, off, 64);
        acc0.y += __shfl_xor(acc0.y, off, 64);
        acc0.z += __shfl_xor(acc0.z, off, 64);
        acc0.w += __shfl_xor(acc0.w, off, 64);
    }

    if (g == 0) {
        float s = dis[wid];
        float s2 = s * s;
        acc0.x *= s2; acc0.y *= s2; acc0.z *= s2; acc0.w *= s2;
        size_t o = (size_t)wid * DIM + l * 4;
        if (MODE != 2) {
            *reinterpret_cast<float4*>(&x_new[o]) = acc0;
        }
        float4 a;
        if (MODE == 0) {
            a = *reinterpret_cast<const float4*>(&base[o]);
        } else {
            a = *reinterpret_cast<const float4*>(&out[o]);
        }
        a.x += acc0.x; a.y += acc0.y; a.z += acc0.z; a.w += acc0.w;
        if (MODE == 2) {
            a.x *= 0.25f; a.y *= 0.25f; a.z *= 0.25f; a.w *= 0.25f;
        }
        *reinterpret_cast<float4*>(&out[o]) = a;
    }
}

extern "C" void kernel_launch(void* const* d_in, const int* in_sizes, int n_in,
                              void* d_out, int out_size, void* d_ws, size_t ws_size,
                              hipStream_t stream) {
    const int* edge = (const int*)d_in[0];       // (2, E) int32
    const int* row = edge;
    const int* col = edge + N_EDGES;
    const float* emb = (const float*)d_in[1];    // (N, 64) f32
    float* out = (float*)d_out;                  // (N, 64) f32

    char* ws = (char*)d_ws;
    size_t off = 0;
    auto alloc = [&](size_t bytes) {
        char* p = ws + off;
        off += (bytes + 255) & ~(size_t)255;
        return p;
    };
    int*   deg      = (int*)alloc((size_t)N_NODES * sizeof(int));
    int*   cursor   = deg;  // aliased: deg dead after emit_kernel
    int*   row_ptr  = (int*)alloc(((size_t)N_NODES + 1) * sizeof(int));
    float* dis      = (float*)alloc((size_t)N_NODES * sizeof(float));
    int*   blocksum = (int*)alloc((size_t)SCAN_BLOCKS * sizeof(int));
    int*   csr_col  = (int*)alloc((size_t)N_EDGES * sizeof(int));
    float* bufA     = (float*)alloc((size_t)N_NODES * DIM * sizeof(float));
    float* bufB     = (float*)alloc((size_t)N_NODES * DIM * sizeof(float));

    const int gather_blocks = (N_NODES * 64 + 255) / 256;  // one wave per node
    const int chunk = (N_NODES + SCAN_BLOCKS - 1) / SCAN_BLOCKS;

    // CSR build (recomputed every call)
    hipMemsetAsync(deg, 0, (size_t)N_NODES * sizeof(int), stream);
    deg_kernel<<<2048, 256, 0, stream>>>(row, deg, N_EDGES);
    partial_kernel<<<SCAN_BLOCKS, 256, 0, stream>>>(deg, blocksum, N_NODES, chunk);
    scan_small_kernel<<<1, SCAN_BLOCKS, 0, stream>>>(blocksum, row_ptr, N_NODES);
    emit_kernel<<<SCAN_BLOCKS, 256, 0, stream>>>(deg, blocksum, row_ptr, cursor, dis,
                                                 N_NODES, chunk);
    fill_kernel<<<2048, 256, 0, stream>>>(row, col, cursor, csr_col, N_EDGES);

    // 3 fused propagate+accumulate layers (no atomics, no big memsets)
    gather_kernel<0><<<gather_blocks, 256, 0, stream>>>(row_ptr, csr_col, dis, emb, bufA, emb, out, N_NODES);
    gather_kernel<1><<<gather_blocks, 256, 0, stream>>>(row_ptr, csr_col, dis, bufA, bufB, nullptr, out, N_NODES);
    gather_kernel<2><<<gather_blocks, 256, 0, stream>>>(row_ptr, csr_col, dis, bufB, nullptr, nullptr, out, N_NODES);
}

// Round 5
// 257.191 us; speedup vs baseline: 3.5162x; 1.1154x over previous
//
#include <hip/hip_runtime.h>
#include <math.h>

#define N_NODES 100000
#define DIM 64
#define N_EDGES 1250000
#define SCAN_BLOCKS 256
#define NRANGE 8
#define RANGE_ROWS ((N_NODES + NRANGE - 1) / NRANGE)   // 12500 rows per XCD-range

typedef unsigned short ushort_t;
typedef unsigned int uint_t;

// bf16 (storage) <-> f32 (compute) helpers
__device__ __forceinline__ float bflo(uint_t u) {          // low 16 bits -> f32
    u <<= 16;
    return __builtin_bit_cast(float, u);
}
__device__ __forceinline__ float bfhi(uint_t u) {          // high 16 bits -> f32
    u &= 0xFFFF0000u;
    return __builtin_bit_cast(float, u);
}
__device__ __forceinline__ uint_t f2bf(float f) {          // round-to-nearest-even
    uint_t u = __builtin_bit_cast(uint_t, f);
    u += 0x7FFFu + ((u >> 16) & 1u);
    return u >> 16;
}

// ---------------------------------------------------------------------------
// deg[i] = #edges with row == i  (int histogram)
__global__ void deg_kernel(const int* __restrict__ row, int* __restrict__ deg, int E) {
    int tid = blockIdx.x * blockDim.x + threadIdx.x;
    int stride = gridDim.x * blockDim.x;
    for (int e = tid; e < E; e += stride) {
        atomicAdd(&deg[row[e]], 1);
    }
}

// emb (f32) -> embh (bf16), 8 elements per thread
__global__ void conv_kernel(const float* __restrict__ emb, ushort_t* __restrict__ embh, int n8) {
    int i = blockIdx.x * blockDim.x + threadIdx.x;
    if (i < n8) {
        float4 a = reinterpret_cast<const float4*>(emb)[2 * i];
        float4 b = reinterpret_cast<const float4*>(emb)[2 * i + 1];
        uint4 w;
        w.x = f2bf(a.x) | (f2bf(a.y) << 16);
        w.y = f2bf(a.z) | (f2bf(a.w) << 16);
        w.z = f2bf(b.x) | (f2bf(b.y) << 16);
        w.w = f2bf(b.z) | (f2bf(b.w) << 16);
        reinterpret_cast<uint4*>(embh)[i] = w;
    }
}

// ---- 3-kernel device-wide exclusive scan of deg ---------------------------
__global__ void partial_kernel(const int* __restrict__ deg, int* __restrict__ blocksum,
                               int N, int chunk) {
    __shared__ int sh[256];
    int b = blockIdx.x;
    int lo = b * chunk, hi = min(lo + chunk, N);
    int s = 0;
    for (int i = lo + (int)threadIdx.x; i < hi; i += 256) s += deg[i];
    sh[threadIdx.x] = s;
    __syncthreads();
    for (int off = 128; off > 0; off >>= 1) {
        if ((int)threadIdx.x < off) sh[threadIdx.x] += sh[threadIdx.x + off];
        __syncthreads();
    }
    if (threadIdx.x == 0) blocksum[b] = sh[0];
}

__global__ void scan_small_kernel(int* __restrict__ blocksum, int* __restrict__ row_ptr, int N) {
    __shared__ int sh[SCAN_BLOCKS];
    int t = threadIdx.x;
    int v = blocksum[t];
    sh[t] = v;
    __syncthreads();
    for (int off = 1; off < SCAN_BLOCKS; off <<= 1) {
        int u = (t >= off) ? sh[t - off] : 0;
        __syncthreads();
        sh[t] += u;
        __syncthreads();
    }
    blocksum[t] = sh[t] - v;  // exclusive = inclusive - own
    if (t == SCAN_BLOCKS - 1) row_ptr[N] = sh[SCAN_BLOCKS - 1];
}

__global__ void emit_kernel(const int* __restrict__ deg, const int* __restrict__ blocksum,
                            int* __restrict__ row_ptr, int* __restrict__ cursor,
                            float* __restrict__ dis, int N, int chunk) {
    __shared__ int sh[256];
    int b = blockIdx.x;
    int t = threadIdx.x;
    int lo = b * chunk, hi = min(lo + chunk, N);
    int running = blocksum[b];
    for (int base = lo; base < hi; base += 256) {
        int i = base + t;
        int d = (i < hi) ? deg[i] : 0;
        sh[t] = d;
        __syncthreads();
        for (int off = 1; off < 256; off <<= 1) {
            int u = (t >= off) ? sh[t - off] : 0;
            __syncthreads();
            sh[t] += u;
            __syncthreads();
        }
        int exc = sh[t] - d;
        if (i < hi) {
            int rp = running + exc;
            row_ptr[i] = rp;
            cursor[i] = rp;
            dis[i] = (d > 0) ? (float)(1.0 / sqrt((double)d)) : 0.0f;
        }
        running += sh[255];
        __syncthreads();
    }
}

// XCD-partitioned CSR fill (kills cross-XCD partial-line write amplification).
__global__ void fill_kernel(const int* __restrict__ row, const int* __restrict__ col,
                            int* __restrict__ cursor, int* __restrict__ csr_col, int E) {
    int rng = blockIdx.x & (NRANGE - 1);
    int cb = blockIdx.x >> 3;
    int cohort_threads = ((int)gridDim.x >> 3) * blockDim.x;
    int tid = cb * blockDim.x + threadIdx.x;
    int lo = rng * RANGE_ROWS;
    for (int e = tid; e < E; e += cohort_threads) {
        int r = row[e];
        if ((unsigned)(r - lo) < (unsigned)RANGE_ROWS) {
            int pos = atomicAdd(&cursor[r], 1);
            csr_col[pos] = col[e];
        }
    }
}

// One wave per node; 8 groups of 8 lanes. Group g loads row csr_col[e] as
// 8 x bf16x8 (16B/lane, 128B/row); lane l owns dims 8l..8l+7 accumulated in
// f32. Cross-group reduce via shfl_xor(8/16/32). Fused epilogue on g==0:
// x_new = bf16(acc*dis^2) and the running f32 `out` accumulation.
// MODE 0: out = base + v          (layer 1, base = emb f32)
// MODE 1: out += v                (layer 2)
// MODE 2: out = (out + v) * 0.25  (layer 3, no x_new store)
template <int MODE>
__global__ void gather_kernel(const int* __restrict__ row_ptr, const int* __restrict__ csr_col,
                              const float* __restrict__ dis,
                              const ushort_t* __restrict__ x_old, ushort_t* __restrict__ x_new,
                              const float* __restrict__ base, float* __restrict__ out, int N) {
    int wid = (int)((blockIdx.x * (size_t)blockDim.x + threadIdx.x) >> 6);
    if (wid >= N) return;
    int lane = threadIdx.x & 63;
    int g = lane >> 3;   // edge-group 0..7
    int l = lane & 7;    // lane within group: owns dims 8l..8l+7

    int start = row_ptr[wid];
    int end = row_ptr[wid + 1];

    float acc[8];
    #pragma unroll
    for (int k = 0; k < 8; ++k) acc[k] = 0.f;

    int e = start + g;
    // unroll-by-2 per group: 16 rows in flight per wave iteration
    for (; e + 8 < end; e += 16) {
        int c0 = csr_col[e];
        int c1 = csr_col[e + 8];
        uint4 v0 = *reinterpret_cast<const uint4*>(&x_old[(size_t)c0 * DIM + l * 8]);
        uint4 v1 = *reinterpret_cast<const uint4*>(&x_old[(size_t)c1 * DIM + l * 8]);
        acc[0] += bflo(v0.x); acc[1] += bfhi(v0.x);
        acc[2] += bflo(v0.y); acc[3] += bfhi(v0.y);
        acc[4] += bflo(v0.z); acc[5] += bfhi(v0.z);
        acc[6] += bflo(v0.w); acc[7] += bfhi(v0.w);
        acc[0] += bflo(v1.x); acc[1] += bfhi(v1.x);
        acc[2] += bflo(v1.y); acc[3] += bfhi(v1.y);
        acc[4] += bflo(v1.z); acc[5] += bfhi(v1.z);
        acc[6] += bflo(v1.w); acc[7] += bfhi(v1.w);
    }
    if (e < end) {
        int c0 = csr_col[e];
        uint4 v0 = *reinterpret_cast<const uint4*>(&x_old[(size_t)c0 * DIM + l * 8]);
        acc[0] += bflo(v0.x); acc[1] += bfhi(v0.x);
        acc[2] += bflo(v0.y); acc[3] += bfhi(v0.y);
        acc[4] += bflo(v0.z); acc[5] += bfhi(v0.z);
        acc[6] += bflo(v0.w); acc[7] += bfhi(v0.w);
    }

    // sum the 8 groups (lanes l, l+8, ..., l+56 hold the same dims)
    #pragma unroll
    for (int off = 8; off <= 32; off <<= 1) {
        #pragma unroll
        for (int k = 0; k < 8; ++k) acc[k] += __shfl_xor(acc[k], off, 64);
    }

    if (g == 0) {
        float s = dis[wid];
        float s2 = s * s;
        #pragma unroll
        for (int k = 0; k < 8; ++k) acc[k] *= s2;
        size_t o = (size_t)wid * DIM + l * 8;
        if (MODE != 2) {
            uint4 w;
            w.x = f2bf(acc[0]) | (f2bf(acc[1]) << 16);
            w.y = f2bf(acc[2]) | (f2bf(acc[3]) << 16);
            w.z = f2bf(acc[4]) | (f2bf(acc[5]) << 16);
            w.w = f2bf(acc[6]) | (f2bf(acc[7]) << 16);
            *reinterpret_cast<uint4*>(&x_new[o]) = w;
        }
        const float* src = (MODE == 0) ? base : out;
        float4 a0 = *reinterpret_cast<const float4*>(&src[o]);
        float4 a1 = *reinterpret_cast<const float4*>(&src[o + 4]);
        a0.x += acc[0]; a0.y += acc[1]; a0.z += acc[2]; a0.w += acc[3];
        a1.x += acc[4]; a1.y += acc[5]; a1.z += acc[6]; a1.w += acc[7];
        if (MODE == 2) {
            a0.x *= 0.25f; a0.y *= 0.25f; a0.z *= 0.25f; a0.w *= 0.25f;
            a1.x *= 0.25f; a1.y *= 0.25f; a1.z *= 0.25f; a1.w *= 0.25f;
        }
        *reinterpret_cast<float4*>(&out[o]) = a0;
        *reinterpret_cast<float4*>(&out[o + 4]) = a1;
    }
}

extern "C" void kernel_launch(void* const* d_in, const int* in_sizes, int n_in,
                              void* d_out, int out_size, void* d_ws, size_t ws_size,
                              hipStream_t stream) {
    const int* edge = (const int*)d_in[0];       // (2, E) int32
    const int* row = edge;
    const int* col = edge + N_EDGES;
    const float* emb = (const float*)d_in[1];    // (N, 64) f32
    float* out = (float*)d_out;                  // (N, 64) f32

    char* ws = (char*)d_ws;
    size_t off = 0;
    auto alloc = [&](size_t bytes) {
        char* p = ws + off;
        off += (bytes + 255) & ~(size_t)255;
        return p;
    };
    int*      deg      = (int*)alloc((size_t)N_NODES * sizeof(int));
    int*      cursor   = deg;  // aliased: deg dead after emit_kernel
    int*      row_ptr  = (int*)alloc(((size_t)N_NODES + 1) * sizeof(int));
    float*    dis      = (float*)alloc((size_t)N_NODES * sizeof(float));
    int*      blocksum = (int*)alloc((size_t)SCAN_BLOCKS * sizeof(int));
    int*      csr_col  = (int*)alloc((size_t)N_EDGES * sizeof(int));
    ushort_t* embh     = (ushort_t*)alloc((size_t)N_NODES * DIM * sizeof(ushort_t));
    ushort_t* bufA     = (ushort_t*)alloc((size_t)N_NODES * DIM * sizeof(ushort_t));
    ushort_t* bufB     = (ushort_t*)alloc((size_t)N_NODES * DIM * sizeof(ushort_t));

    const int gather_blocks = (N_NODES * 64 + 255) / 256;  // one wave per node
    const int chunk = (N_NODES + SCAN_BLOCKS - 1) / SCAN_BLOCKS;

    // CSR build (recomputed every call) + emb->bf16 conversion
    hipMemsetAsync(deg, 0, (size_t)N_NODES * sizeof(int), stream);
    deg_kernel<<<2048, 256, 0, stream>>>(row, deg, N_EDGES);
    conv_kernel<<<(N_NODES * DIM / 8 + 255) / 256, 256, 0, stream>>>(emb, embh, N_NODES * DIM / 8);
    partial_kernel<<<SCAN_BLOCKS, 256, 0, stream>>>(deg, blocksum, N_NODES, chunk);
    scan_small_kernel<<<1, SCAN_BLOCKS, 0, stream>>>(blocksum, row_ptr, N_NODES);
    emit_kernel<<<SCAN_BLOCKS, 256, 0, stream>>>(deg, blocksum, row_ptr, cursor, dis,
                                                 N_NODES, chunk);
    fill_kernel<<<2048, 256, 0, stream>>>(row, col, cursor, csr_col, N_EDGES);

    // 3 fused propagate+accumulate layers (bf16 x-storage, f32 accumulation)
    gather_kernel<0><<<gather_blocks, 256, 0, stream>>>(row_ptr, csr_col, dis, embh, bufA, emb, out, N_NODES);
    gather_kernel<1><<<gather_blocks, 256, 0, stream>>>(row_ptr, csr_col, dis, bufA, bufB, nullptr, out, N_NODES);
    gather_kernel<2><<<gather_blocks, 256, 0, stream>>>(row_ptr, csr_col, dis, bufB, nullptr, nullptr, out, N_NODES);
}

// Round 6
// 181.430 us; speedup vs baseline: 4.9845x; 1.4176x over previous
//
#include <hip/hip_runtime.h>
#include <math.h>

#define N_NODES 100000
#define DIM 64
#define N_EDGES 1250000
#define SCAN_BLOCKS 256
#define RPB 128                                   // rows per bucket (row>>7)
#define NB_BUCKETS ((N_NODES + RPB - 1) / RPB)    // 782
#define NBLK_B 128                                // blocks in hist/scatter pass
#define CNT_N (NB_BUCKETS * NBLK_B)               // 100096 = 391*256
#define CAP 2048                                  // max edges per bucket (mean 1600, sd 40)

typedef unsigned short ushort_t;
typedef unsigned int uint_t;

// bf16 (storage) <-> f32 (compute) helpers
__device__ __forceinline__ float bflo(uint_t u) { u <<= 16; return __builtin_bit_cast(float, u); }
__device__ __forceinline__ float bfhi(uint_t u) { u &= 0xFFFF0000u; return __builtin_bit_cast(float, u); }
__device__ __forceinline__ uint_t f2bf(float f) {
    uint_t u = __builtin_bit_cast(uint_t, f);
    u += 0x7FFFu + ((u >> 16) & 1u);
    return u >> 16;
}

// emb (f32) -> embh (bf16), 8 elements per thread
__global__ void conv_kernel(const float* __restrict__ emb, ushort_t* __restrict__ embh, int n8) {
    int i = blockIdx.x * blockDim.x + threadIdx.x;
    if (i < n8) {
        float4 a = reinterpret_cast<const float4*>(emb)[2 * i];
        float4 b = reinterpret_cast<const float4*>(emb)[2 * i + 1];
        uint4 w;
        w.x = f2bf(a.x) | (f2bf(a.y) << 16);
        w.y = f2bf(a.z) | (f2bf(a.w) << 16);
        w.z = f2bf(b.x) | (f2bf(b.y) << 16);
        w.w = f2bf(b.z) | (f2bf(b.w) << 16);
        reinterpret_cast<uint4*>(embh)[i] = w;
    }
}

// ---- bucket pass 1: per-block histogram over buckets (bucket-major out) ---
__global__ void bucket_hist_kernel(const int* __restrict__ row, int* __restrict__ cnt, int E) {
    __shared__ int h[NB_BUCKETS];
    for (int i = threadIdx.x; i < NB_BUCKETS; i += blockDim.x) h[i] = 0;
    __syncthreads();
    int blk = blockIdx.x;
    int per = (E + (int)gridDim.x - 1) / (int)gridDim.x;
    int lo = blk * per, hi = min(lo + per, E);
    for (int e = lo + (int)threadIdx.x; e < hi; e += blockDim.x)
        atomicAdd(&h[row[e] >> 7], 1);
    __syncthreads();
    for (int b = threadIdx.x; b < NB_BUCKETS; b += blockDim.x)
        cnt[b * NBLK_B + blk] = h[b];   // bucket-major: scan order = slot order
}

// ---- generic 3-kernel device-wide exclusive scan ---------------------------
__global__ void partial_kernel(const int* __restrict__ in, int* __restrict__ blocksum,
                               int N, int chunk) {
    __shared__ int sh[256];
    int b = blockIdx.x;
    int lo = b * chunk, hi = min(lo + chunk, N);
    int s = 0;
    for (int i = lo + (int)threadIdx.x; i < hi; i += 256) s += in[i];
    sh[threadIdx.x] = s;
    __syncthreads();
    for (int off = 128; off > 0; off >>= 1) {
        if ((int)threadIdx.x < off) sh[threadIdx.x] += sh[threadIdx.x + off];
        __syncthreads();
    }
    if (threadIdx.x == 0) blocksum[b] = sh[0];
}

__global__ void scan_small_kernel(int* __restrict__ blocksum, int* __restrict__ out, int N) {
    __shared__ int sh[SCAN_BLOCKS];
    int t = threadIdx.x;
    int v = blocksum[t];
    sh[t] = v;
    __syncthreads();
    for (int off = 1; off < SCAN_BLOCKS; off <<= 1) {
        int u = (t >= off) ? sh[t - off] : 0;
        __syncthreads();
        sh[t] += u;
        __syncthreads();
    }
    blocksum[t] = sh[t] - v;  // exclusive = inclusive - own
    if (t == SCAN_BLOCKS - 1) out[N] = sh[SCAN_BLOCKS - 1];  // total
}

__global__ void scan_emit_kernel(const int* __restrict__ in, const int* __restrict__ blocksum,
                                 int* __restrict__ out, int N, int chunk) {
    __shared__ int sh[256];
    int b = blockIdx.x;
    int t = threadIdx.x;
    int lo = b * chunk, hi = min(lo + chunk, N);
    int running = blocksum[b];
    for (int base = lo; base < hi; base += 256) {
        int i = base + t;
        int d = (i < hi) ? in[i] : 0;
        sh[t] = d;
        __syncthreads();
        for (int off = 1; off < 256; off <<= 1) {
            int u = (t >= off) ? sh[t - off] : 0;
            __syncthreads();
            sh[t] += u;
            __syncthreads();
        }
        if (i < hi) out[i] = running + (sh[t] - d);
        running += sh[255];
        __syncthreads();
    }
}

// ---- bucket pass 2: scatter packed edges into per-(bucket,block) slots ----
// pack = (row&127)<<17 | col  (col < 2^17). Slots are contiguous per block ->
// ~78-edge sequential runs, near-full-line writes, one writer per region.
__global__ void bucket_scatter_kernel(const int* __restrict__ row, const int* __restrict__ col,
                                      const int* __restrict__ slot_off,
                                      int* __restrict__ pairs, int E) {
    __shared__ int cur[NB_BUCKETS];
    int blk = blockIdx.x;
    for (int b = threadIdx.x; b < NB_BUCKETS; b += blockDim.x)
        cur[b] = slot_off[b * NBLK_B + blk];
    __syncthreads();
    int per = (E + (int)gridDim.x - 1) / (int)gridDim.x;
    int lo = blk * per, hi = min(lo + per, E);
    for (int e = lo + (int)threadIdx.x; e < hi; e += blockDim.x) {
        int r = row[e], c = col[e];
        int pos = atomicAdd(&cur[r >> 7], 1);
        pairs[pos] = ((r & (RPB - 1)) << 17) | c;
    }
}

// ---- bucket pass 3: one block per bucket -> row_ptr, dis, csr_col ---------
// Entirely in LDS: local histogram (=true deg), 128-entry scan, edge placement,
// then one contiguous full-line stream-out. Subsumes deg/emit kernels.
__global__ void __launch_bounds__(256) bucket_csr_kernel(
        const int* __restrict__ slot_off, const int* __restrict__ pairs,
        int* __restrict__ row_ptr, float* __restrict__ dis,
        int* __restrict__ csr_col, int E) {
    __shared__ int pk[CAP];
    __shared__ int csr_lds[CAP];
    __shared__ int deg_loc[RPB];
    __shared__ int scan_loc[RPB];
    __shared__ int cur_loc[RPB];
    int b = blockIdx.x;
    int t = threadIdx.x;
    int start = slot_off[b * NBLK_B];
    int end = slot_off[(b + 1) * NBLK_B];   // b=NB-1 reads slot_off[CNT_N]=E
    int cnt = end - start;
    bool fits = (cnt <= CAP);               // statistically always true

    if (t < RPB) deg_loc[t] = 0;
    if (fits) {
        for (int i = t; i < cnt; i += 256) pk[i] = pairs[start + i];
    }
    __syncthreads();
    for (int i = t; i < cnt; i += 256) {
        int p = fits ? pk[i] : pairs[start + i];
        atomicAdd(&deg_loc[p >> 17], 1);
    }
    __syncthreads();
    // exclusive scan of deg_loc[RPB] (Hillis-Steele; uniform barriers)
    int d = (t < RPB) ? deg_loc[t] : 0;
    if (t < RPB) scan_loc[t] = d;
    __syncthreads();
    for (int off = 1; off < RPB; off <<= 1) {
        int v = (t < RPB && t >= off) ? scan_loc[t - off] : 0;
        __syncthreads();
        if (t < RPB) scan_loc[t] += v;
        __syncthreads();
    }
    if (t < RPB) {
        int exc = scan_loc[t] - d;
        cur_loc[t] = exc;
        int rg = b * RPB + t;
        if (rg < N_NODES) {
            row_ptr[rg] = start + exc;
            dis[rg] = (d > 0) ? (float)(1.0 / sqrt((double)d)) : 0.0f;
        }
    }
    __syncthreads();
    // place cols by row within the bucket
    for (int i = t; i < cnt; i += 256) {
        int p = fits ? pk[i] : pairs[start + i];
        int pos = atomicAdd(&cur_loc[p >> 17], 1);
        int c = p & 0x1FFFF;
        if (fits) csr_lds[pos] = c;
        else      csr_col[start + pos] = c;   // rare fallback, scattered
    }
    __syncthreads();
    if (fits) {
        for (int i = t; i < cnt; i += 256) csr_col[start + i] = csr_lds[i];
    }
    if (b == NB_BUCKETS - 1 && t == 0) row_ptr[N_NODES] = E;
}

// One wave per node; 8 groups of 8 lanes. Group g loads row csr_col[e] as
// 8 x bf16x8 (16B/lane, 128B/row); lane l owns dims 8l..8l+7 accumulated in
// f32. Cross-group reduce via shfl_xor(8/16/32). Fused epilogue on g==0.
// MODE 0: out = base + v          (layer 1, base = emb f32)
// MODE 1: out += v                (layer 2)
// MODE 2: out = (out + v) * 0.25  (layer 3, no x_new store)
template <int MODE>
__global__ void gather_kernel(const int* __restrict__ row_ptr, const int* __restrict__ csr_col,
                              const float* __restrict__ dis,
                              const ushort_t* __restrict__ x_old, ushort_t* __restrict__ x_new,
                              const float* __restrict__ base, float* __restrict__ out, int N) {
    int wid = (int)((blockIdx.x * (size_t)blockDim.x + threadIdx.x) >> 6);
    if (wid >= N) return;
    int lane = threadIdx.x & 63;
    int g = lane >> 3;   // edge-group 0..7
    int l = lane & 7;    // lane within group: owns dims 8l..8l+7

    int start = row_ptr[wid];
    int end = row_ptr[wid + 1];

    float acc[8];
    #pragma unroll
    for (int k = 0; k < 8; ++k) acc[k] = 0.f;

    int e = start + g;
    for (; e + 8 < end; e += 16) {
        int c0 = csr_col[e];
        int c1 = csr_col[e + 8];
        uint4 v0 = *reinterpret_cast<const uint4*>(&x_old[(size_t)c0 * DIM + l * 8]);
        uint4 v1 = *reinterpret_cast<const uint4*>(&x_old[(size_t)c1 * DIM + l * 8]);
        acc[0] += bflo(v0.x); acc[1] += bfhi(v0.x);
        acc[2] += bflo(v0.y); acc[3] += bfhi(v0.y);
        acc[4] += bflo(v0.z); acc[5] += bfhi(v0.z);
        acc[6] += bflo(v0.w); acc[7] += bfhi(v0.w);
        acc[0] += bflo(v1.x); acc[1] += bfhi(v1.x);
        acc[2] += bflo(v1.y); acc[3] += bfhi(v1.y);
        acc[4] += bflo(v1.z); acc[5] += bfhi(v1.z);
        acc[6] += bflo(v1.w); acc[7] += bfhi(v1.w);
    }
    if (e < end) {
        int c0 = csr_col[e];
        uint4 v0 = *reinterpret_cast<const uint4*>(&x_old[(size_t)c0 * DIM + l * 8]);
        acc[0] += bflo(v0.x); acc[1] += bfhi(v0.x);
        acc[2] += bflo(v0.y); acc[3] += bfhi(v0.y);
        acc[4] += bflo(v0.z); acc[5] += bfhi(v0.z);
        acc[6] += bflo(v0.w); acc[7] += bfhi(v0.w);
    }

    #pragma unroll
    for (int off = 8; off <= 32; off <<= 1) {
        #pragma unroll
        for (int k = 0; k < 8; ++k) acc[k] += __shfl_xor(acc[k], off, 64);
    }

    if (g == 0) {
        float s = dis[wid];
        float s2 = s * s;
        #pragma unroll
        for (int k = 0; k < 8; ++k) acc[k] *= s2;
        size_t o = (size_t)wid * DIM + l * 8;
        if (MODE != 2) {
            uint4 w;
            w.x = f2bf(acc[0]) | (f2bf(acc[1]) << 16);
            w.y = f2bf(acc[2]) | (f2bf(acc[3]) << 16);
            w.z = f2bf(acc[4]) | (f2bf(acc[5]) << 16);
            w.w = f2bf(acc[6]) | (f2bf(acc[7]) << 16);
            *reinterpret_cast<uint4*>(&x_new[o]) = w;
        }
        const float* src = (MODE == 0) ? base : out;
        float4 a0 = *reinterpret_cast<const float4*>(&src[o]);
        float4 a1 = *reinterpret_cast<const float4*>(&src[o + 4]);
        a0.x += acc[0]; a0.y += acc[1]; a0.z += acc[2]; a0.w += acc[3];
        a1.x += acc[4]; a1.y += acc[5]; a1.z += acc[6]; a1.w += acc[7];
        if (MODE == 2) {
            a0.x *= 0.25f; a0.y *= 0.25f; a0.z *= 0.25f; a0.w *= 0.25f;
            a1.x *= 0.25f; a1.y *= 0.25f; a1.z *= 0.25f; a1.w *= 0.25f;
        }
        *reinterpret_cast<float4*>(&out[o]) = a0;
        *reinterpret_cast<float4*>(&out[o + 4]) = a1;
    }
}

extern "C" void kernel_launch(void* const* d_in, const int* in_sizes, int n_in,
                              void* d_out, int out_size, void* d_ws, size_t ws_size,
                              hipStream_t stream) {
    const int* edge = (const int*)d_in[0];       // (2, E) int32
    const int* row = edge;
    const int* col = edge + N_EDGES;
    const float* emb = (const float*)d_in[1];    // (N, 64) f32
    float* out = (float*)d_out;                  // (N, 64) f32

    char* ws = (char*)d_ws;
    size_t off = 0;
    auto alloc = [&](size_t bytes) {
        char* p = ws + off;
        off += (bytes + 255) & ~(size_t)255;
        return p;
    };
    int*      row_ptr  = (int*)alloc(((size_t)N_NODES + 1) * sizeof(int));
    float*    dis      = (float*)alloc((size_t)N_NODES * sizeof(float));
    int*      blocksum = (int*)alloc((size_t)SCAN_BLOCKS * sizeof(int));
    int*      cnt      = (int*)alloc((size_t)CNT_N * sizeof(int));
    int*      slot_off = (int*)alloc(((size_t)CNT_N + 1) * sizeof(int));
    int*      pairs    = (int*)alloc((size_t)N_EDGES * sizeof(int));
    int*      csr_col  = (int*)alloc((size_t)N_EDGES * sizeof(int));
    ushort_t* embh     = (ushort_t*)alloc((size_t)N_NODES * DIM * sizeof(ushort_t));
    ushort_t* bufA     = (ushort_t*)alloc((size_t)N_NODES * DIM * sizeof(ushort_t));
    ushort_t* bufB     = (ushort_t*)alloc((size_t)N_NODES * DIM * sizeof(ushort_t));

    const int gather_blocks = (N_NODES * 64 + 255) / 256;  // one wave per node
    const int chunk = (CNT_N + SCAN_BLOCKS - 1) / SCAN_BLOCKS;  // 391 exactly

    // CSR build via 2-level bucket sort (no memsets, no f32 atomics,
    // contiguous writes only; also produces deg -> row_ptr/dis)
    conv_kernel<<<(N_NODES * DIM / 8 + 255) / 256, 256, 0, stream>>>(emb, embh, N_NODES * DIM / 8);
    bucket_hist_kernel<<<NBLK_B, 256, 0, stream>>>(row, cnt, N_EDGES);
    partial_kernel<<<SCAN_BLOCKS, 256, 0, stream>>>(cnt, blocksum, CNT_N, chunk);
    scan_small_kernel<<<1, SCAN_BLOCKS, 0, stream>>>(blocksum, slot_off, CNT_N);
    scan_emit_kernel<<<SCAN_BLOCKS, 256, 0, stream>>>(cnt, blocksum, slot_off, CNT_N, chunk);
    bucket_scatter_kernel<<<NBLK_B, 256, 0, stream>>>(row, col, slot_off, pairs, N_EDGES);
    bucket_csr_kernel<<<NB_BUCKETS, 256, 0, stream>>>(slot_off, pairs, row_ptr, dis, csr_col, N_EDGES);

    // 3 fused propagate+accumulate layers (bf16 x-storage, f32 accumulation)
    gather_kernel<0><<<gather_blocks, 256, 0, stream>>>(row_ptr, csr_col, dis, embh, bufA, emb, out, N_NODES);
    gather_kernel<1><<<gather_blocks, 256, 0, stream>>>(row_ptr, csr_col, dis, bufA, bufB, nullptr, out, N_NODES);
    gather_kernel<2><<<gather_blocks, 256, 0, stream>>>(row_ptr, csr_col, dis, bufB, nullptr, nullptr, out, N_NODES);
}

// Round 7
// 152.850 us; speedup vs baseline: 5.9165x; 1.1870x over previous
//
#include <hip/hip_runtime.h>
#include <math.h>

#define N_NODES 100000
#define DIM 64
#define N_EDGES 1250000
#define SCAN_BLOCKS 256
#define RPB 128                                   // rows per bucket (row>>7)
#define NB_BUCKETS ((N_NODES + RPB - 1) / RPB)    // 782
#define NBLK_B 128                                // blocks in hist/scatter pass
#define CNT_N (NB_BUCKETS * NBLK_B)               // 100096 = 391*256
#define CAP 2048                                  // max edges per bucket (mean 1600)

typedef unsigned short ushort_t;
typedef unsigned int uint_t;

// fp16 (storage) <-> f32 (compute) helpers. fp16 chosen over bf16: values are
// tiny (|x| <~ 1e-2, well inside fp16 range) so the 10-bit mantissa gives 8x
// less rounding error -- needed because the final combine sums 16-bit x_k.
__device__ __forceinline__ float hlo(uint_t u) {
    return (float)__builtin_bit_cast(_Float16, (ushort_t)(u & 0xFFFFu));
}
__device__ __forceinline__ float hhi(uint_t u) {
    return (float)__builtin_bit_cast(_Float16, (ushort_t)(u >> 16));
}
__device__ __forceinline__ uint_t f2h(float f) {   // RTNE via v_cvt_f16_f32
    return (uint_t)__builtin_bit_cast(ushort_t, (_Float16)f);
}

// emb (f32) -> embh (fp16), 8 elements per thread
__global__ void conv_kernel(const float* __restrict__ emb, ushort_t* __restrict__ embh, int n8) {
    int i = blockIdx.x * blockDim.x + threadIdx.x;
    if (i < n8) {
        float4 a = reinterpret_cast<const float4*>(emb)[2 * i];
        float4 b = reinterpret_cast<const float4*>(emb)[2 * i + 1];
        uint4 w;
        w.x = f2h(a.x) | (f2h(a.y) << 16);
        w.y = f2h(a.z) | (f2h(a.w) << 16);
        w.z = f2h(b.x) | (f2h(b.y) << 16);
        w.w = f2h(b.z) | (f2h(b.w) << 16);
        reinterpret_cast<uint4*>(embh)[i] = w;
    }
}

// ---- bucket pass 1: per-block histogram over buckets (bucket-major out) ---
__global__ void bucket_hist_kernel(const int* __restrict__ row, int* __restrict__ cnt, int E) {
    __shared__ int h[NB_BUCKETS];
    for (int i = threadIdx.x; i < NB_BUCKETS; i += blockDim.x) h[i] = 0;
    __syncthreads();
    int blk = blockIdx.x;
    int per = (E + (int)gridDim.x - 1) / (int)gridDim.x;
    int lo = blk * per, hi = min(lo + per, E);
    for (int e = lo + (int)threadIdx.x; e < hi; e += blockDim.x)
        atomicAdd(&h[row[e] >> 7], 1);
    __syncthreads();
    for (int b = threadIdx.x; b < NB_BUCKETS; b += blockDim.x)
        cnt[b * NBLK_B + blk] = h[b];   // bucket-major: scan order = slot order
}

// ---- generic 3-kernel device-wide exclusive scan ---------------------------
__global__ void partial_kernel(const int* __restrict__ in, int* __restrict__ blocksum,
                               int N, int chunk) {
    __shared__ int sh[256];
    int b = blockIdx.x;
    int lo = b * chunk, hi = min(lo + chunk, N);
    int s = 0;
    for (int i = lo + (int)threadIdx.x; i < hi; i += 256) s += in[i];
    sh[threadIdx.x] = s;
    __syncthreads();
    for (int off = 128; off > 0; off >>= 1) {
        if ((int)threadIdx.x < off) sh[threadIdx.x] += sh[threadIdx.x + off];
        __syncthreads();
    }
    if (threadIdx.x == 0) blocksum[b] = sh[0];
}

__global__ void scan_small_kernel(int* __restrict__ blocksum, int* __restrict__ out, int N) {
    __shared__ int sh[SCAN_BLOCKS];
    int t = threadIdx.x;
    int v = blocksum[t];
    sh[t] = v;
    __syncthreads();
    for (int off = 1; off < SCAN_BLOCKS; off <<= 1) {
        int u = (t >= off) ? sh[t - off] : 0;
        __syncthreads();
        sh[t] += u;
        __syncthreads();
    }
    blocksum[t] = sh[t] - v;  // exclusive = inclusive - own
    if (t == SCAN_BLOCKS - 1) out[N] = sh[SCAN_BLOCKS - 1];  // total
}

__global__ void scan_emit_kernel(const int* __restrict__ in, const int* __restrict__ blocksum,
                                 int* __restrict__ out, int N, int chunk) {
    __shared__ int sh[256];
    int b = blockIdx.x;
    int t = threadIdx.x;
    int lo = b * chunk, hi = min(lo + chunk, N);
    int running = blocksum[b];
    for (int base = lo; base < hi; base += 256) {
        int i = base + t;
        int d = (i < hi) ? in[i] : 0;
        sh[t] = d;
        __syncthreads();
        for (int off = 1; off < 256; off <<= 1) {
            int u = (t >= off) ? sh[t - off] : 0;
            __syncthreads();
            sh[t] += u;
            __syncthreads();
        }
        if (i < hi) out[i] = running + (sh[t] - d);
        running += sh[255];
        __syncthreads();
    }
}

// ---- bucket pass 2: scatter packed edges into per-(bucket,block) slots ----
__global__ void bucket_scatter_kernel(const int* __restrict__ row, const int* __restrict__ col,
                                      const int* __restrict__ slot_off,
                                      int* __restrict__ pairs, int E) {
    __shared__ int cur[NB_BUCKETS];
    int blk = blockIdx.x;
    for (int b = threadIdx.x; b < NB_BUCKETS; b += blockDim.x)
        cur[b] = slot_off[b * NBLK_B + blk];
    __syncthreads();
    int per = (E + (int)gridDim.x - 1) / (int)gridDim.x;
    int lo = blk * per, hi = min(lo + per, E);
    for (int e = lo + (int)threadIdx.x; e < hi; e += blockDim.x) {
        int r = row[e], c = col[e];
        int pos = atomicAdd(&cur[r >> 7], 1);
        pairs[pos] = ((r & (RPB - 1)) << 17) | c;
    }
}

// ---- bucket pass 3: one block per bucket -> row_ptr, dis, csr_col ---------
__global__ void __launch_bounds__(256) bucket_csr_kernel(
        const int* __restrict__ slot_off, const int* __restrict__ pairs,
        int* __restrict__ row_ptr, float* __restrict__ dis,
        int* __restrict__ csr_col, int E) {
    __shared__ int pk[CAP];
    __shared__ int csr_lds[CAP];
    __shared__ int deg_loc[RPB];
    __shared__ int scan_loc[RPB];
    __shared__ int cur_loc[RPB];
    int b = blockIdx.x;
    int t = threadIdx.x;
    int start = slot_off[b * NBLK_B];
    int end = slot_off[(b + 1) * NBLK_B];   // b=NB-1 reads slot_off[CNT_N]=E
    int cnt = end - start;
    bool fits = (cnt <= CAP);

    if (t < RPB) deg_loc[t] = 0;
    if (fits) {
        for (int i = t; i < cnt; i += 256) pk[i] = pairs[start + i];
    }
    __syncthreads();
    for (int i = t; i < cnt; i += 256) {
        int p = fits ? pk[i] : pairs[start + i];
        atomicAdd(&deg_loc[p >> 17], 1);
    }
    __syncthreads();
    int d = (t < RPB) ? deg_loc[t] : 0;
    if (t < RPB) scan_loc[t] = d;
    __syncthreads();
    for (int off = 1; off < RPB; off <<= 1) {
        int v = (t < RPB && t >= off) ? scan_loc[t - off] : 0;
        __syncthreads();
        if (t < RPB) scan_loc[t] += v;
        __syncthreads();
    }
    if (t < RPB) {
        int exc = scan_loc[t] - d;
        cur_loc[t] = exc;
        int rg = b * RPB + t;
        if (rg < N_NODES) {
            row_ptr[rg] = start + exc;
            dis[rg] = (d > 0) ? (float)(1.0 / sqrt((double)d)) : 0.0f;
        }
    }
    __syncthreads();
    for (int i = t; i < cnt; i += 256) {
        int p = fits ? pk[i] : pairs[start + i];
        int pos = atomicAdd(&cur_loc[p >> 17], 1);
        int c = p & 0x1FFFF;
        if (fits) csr_lds[pos] = c;
        else      csr_col[start + pos] = c;
    }
    __syncthreads();
    if (fits) {
        for (int i = t; i < cnt; i += 256) csr_col[start + i] = csr_lds[i];
    }
    if (b == NB_BUCKETS - 1 && t == 0) row_ptr[N_NODES] = E;
}

// Two nodes per wave: lanes 0-31 -> node 2w, lanes 32-63 -> node 2w+1.
// Within a node: 4 groups of 8 lanes; group g handles edges start+g, +4, ...
// Each group loads one full fp16 row (8 lanes x 16B = 128B). Cross-group
// reduce via shfl_xor(8,16) (stays within the 32-lane half). No out-RMW:
// only x_new = fp16(acc * dis^2) is written (output deferred to combine).
__global__ void gather_kernel(const int* __restrict__ row_ptr, const int* __restrict__ csr_col,
                              const float* __restrict__ dis,
                              const ushort_t* __restrict__ x_old, ushort_t* __restrict__ x_new,
                              int Npair) {
    int wid = (int)((blockIdx.x * (size_t)blockDim.x + threadIdx.x) >> 6);
    if (wid >= Npair) return;
    int lane = threadIdx.x & 63;
    int sub = lane >> 5;   // which node of the pair
    int l5 = lane & 31;
    int g = l5 >> 3;       // edge-group 0..3 within node
    int l = l5 & 7;        // lane within group: owns dims 8l..8l+7
    int node = wid * 2 + sub;

    int start = row_ptr[node];
    int end = row_ptr[node + 1];

    float acc[8];
    #pragma unroll
    for (int k = 0; k < 8; ++k) acc[k] = 0.f;

    int e = start + g;
    // unroll-by-2 per group: 2 outstanding row loads
    for (; e + 4 < end; e += 8) {
        int c0 = csr_col[e];
        int c1 = csr_col[e + 4];
        uint4 v0 = *reinterpret_cast<const uint4*>(&x_old[(size_t)c0 * DIM + l * 8]);
        uint4 v1 = *reinterpret_cast<const uint4*>(&x_old[(size_t)c1 * DIM + l * 8]);
        acc[0] += hlo(v0.x); acc[1] += hhi(v0.x);
        acc[2] += hlo(v0.y); acc[3] += hhi(v0.y);
        acc[4] += hlo(v0.z); acc[5] += hhi(v0.z);
        acc[6] += hlo(v0.w); acc[7] += hhi(v0.w);
        acc[0] += hlo(v1.x); acc[1] += hhi(v1.x);
        acc[2] += hlo(v1.y); acc[3] += hhi(v1.y);
        acc[4] += hlo(v1.z); acc[5] += hhi(v1.z);
        acc[6] += hlo(v1.w); acc[7] += hhi(v1.w);
    }
    if (e < end) {
        int c0 = csr_col[e];
        uint4 v0 = *reinterpret_cast<const uint4*>(&x_old[(size_t)c0 * DIM + l * 8]);
        acc[0] += hlo(v0.x); acc[1] += hhi(v0.x);
        acc[2] += hlo(v0.y); acc[3] += hhi(v0.y);
        acc[4] += hlo(v0.z); acc[5] += hhi(v0.z);
        acc[6] += hlo(v0.w); acc[7] += hhi(v0.w);
    }

    // sum the 4 groups within this 32-lane half
    #pragma unroll
    for (int off = 8; off <= 16; off <<= 1) {
        #pragma unroll
        for (int k = 0; k < 8; ++k) acc[k] += __shfl_xor(acc[k], off, 64);
    }

    if (g == 0) {
        float s = dis[node];
        float s2 = s * s;
        uint4 w;
        w.x = f2h(acc[0] * s2) | (f2h(acc[1] * s2) << 16);
        w.y = f2h(acc[2] * s2) | (f2h(acc[3] * s2) << 16);
        w.z = f2h(acc[4] * s2) | (f2h(acc[5] * s2) << 16);
        w.w = f2h(acc[6] * s2) | (f2h(acc[7] * s2) << 16);
        *reinterpret_cast<uint4*>(&x_new[(size_t)node * DIM + l * 8]) = w;
    }
}

// out = 0.25 * (embh + x1 + x2 + x3), 8 elements per thread. All inputs fp16
// and L3-hot (just written); single streaming pass.
__global__ void combine_kernel(const ushort_t* __restrict__ e0, const ushort_t* __restrict__ x1,
                               const ushort_t* __restrict__ x2, const ushort_t* __restrict__ x3,
                               float* __restrict__ out, int n8) {
    int i = blockIdx.x * blockDim.x + threadIdx.x;
    if (i < n8) {
        uint4 a = reinterpret_cast<const uint4*>(e0)[i];
        uint4 b = reinterpret_cast<const uint4*>(x1)[i];
        uint4 c = reinterpret_cast<const uint4*>(x2)[i];
        uint4 d = reinterpret_cast<const uint4*>(x3)[i];
        float4 r0, r1;
        r0.x = (hlo(a.x) + hlo(b.x) + hlo(c.x) + hlo(d.x)) * 0.25f;
        r0.y = (hhi(a.x) + hhi(b.x) + hhi(c.x) + hhi(d.x)) * 0.25f;
        r0.z = (hlo(a.y) + hlo(b.y) + hlo(c.y) + hlo(d.y)) * 0.25f;
        r0.w = (hhi(a.y) + hhi(b.y) + hhi(c.y) + hhi(d.y)) * 0.25f;
        r1.x = (hlo(a.z) + hlo(b.z) + hlo(c.z) + hlo(d.z)) * 0.25f;
        r1.y = (hhi(a.z) + hhi(b.z) + hhi(c.z) + hhi(d.z)) * 0.25f;
        r1.z = (hlo(a.w) + hlo(b.w) + hlo(c.w) + hlo(d.w)) * 0.25f;
        r1.w = (hhi(a.w) + hhi(b.w) + hhi(c.w) + hhi(d.w)) * 0.25f;
        reinterpret_cast<float4*>(out)[2 * i] = r0;
        reinterpret_cast<float4*>(out)[2 * i + 1] = r1;
    }
}

extern "C" void kernel_launch(void* const* d_in, const int* in_sizes, int n_in,
                              void* d_out, int out_size, void* d_ws, size_t ws_size,
                              hipStream_t stream) {
    const int* edge = (const int*)d_in[0];       // (2, E) int32
    const int* row = edge;
    const int* col = edge + N_EDGES;
    const float* emb = (const float*)d_in[1];    // (N, 64) f32
    float* out = (float*)d_out;                  // (N, 64) f32

    char* ws = (char*)d_ws;
    size_t off = 0;
    auto alloc = [&](size_t bytes) {
        char* p = ws + off;
        off += (bytes + 255) & ~(size_t)255;
        return p;
    };
    int*      row_ptr  = (int*)alloc(((size_t)N_NODES + 1) * sizeof(int));
    float*    dis      = (float*)alloc((size_t)N_NODES * sizeof(float));
    int*      blocksum = (int*)alloc((size_t)SCAN_BLOCKS * sizeof(int));
    int*      cnt      = (int*)alloc((size_t)CNT_N * sizeof(int));
    int*      slot_off = (int*)alloc(((size_t)CNT_N + 1) * sizeof(int));
    int*      csr_col  = (int*)alloc((size_t)N_EDGES * sizeof(int));
    ushort_t* embh     = (ushort_t*)alloc((size_t)N_NODES * DIM * sizeof(ushort_t));
    ushort_t* x1       = (ushort_t*)alloc((size_t)N_NODES * DIM * sizeof(ushort_t));
    ushort_t* x2       = (ushort_t*)alloc((size_t)N_NODES * DIM * sizeof(ushort_t));
    ushort_t* x3       = (ushort_t*)alloc((size_t)N_NODES * DIM * sizeof(ushort_t));
    // pairs (5MB) aliases x2 (12.8MB): pairs is dead after bucket_csr_kernel,
    // x2 is first written by the second gather (later) -> lifetimes disjoint.
    int*      pairs    = (int*)x2;

    const int gather_blocks = (N_NODES / 2 * 64) / 256;   // 2 nodes per wave
    const int chunk = (CNT_N + SCAN_BLOCKS - 1) / SCAN_BLOCKS;
    const int n8 = N_NODES * DIM / 8;

    // CSR build via 2-level bucket sort + emb->fp16 conversion
    conv_kernel<<<(n8 + 255) / 256, 256, 0, stream>>>(emb, embh, n8);
    bucket_hist_kernel<<<NBLK_B, 256, 0, stream>>>(row, cnt, N_EDGES);
    partial_kernel<<<SCAN_BLOCKS, 256, 0, stream>>>(cnt, blocksum, CNT_N, chunk);
    scan_small_kernel<<<1, SCAN_BLOCKS, 0, stream>>>(blocksum, slot_off, CNT_N);
    scan_emit_kernel<<<SCAN_BLOCKS, 256, 0, stream>>>(cnt, blocksum, slot_off, CNT_N, chunk);
    bucket_scatter_kernel<<<NBLK_B, 256, 0, stream>>>(row, col, slot_off, pairs, N_EDGES);
    bucket_csr_kernel<<<NB_BUCKETS, 256, 0, stream>>>(slot_off, pairs, row_ptr, dis, csr_col, N_EDGES);

    // 3 propagate layers (fp16 storage, f32 accumulate; no out-RMW traffic)
    gather_kernel<<<gather_blocks, 256, 0, stream>>>(row_ptr, csr_col, dis, embh, x1, N_NODES / 2);
    gather_kernel<<<gather_blocks, 256, 0, stream>>>(row_ptr, csr_col, dis, x1, x2, N_NODES / 2);
    gather_kernel<<<gather_blocks, 256, 0, stream>>>(row_ptr, csr_col, dis, x2, x3, N_NODES / 2);

    // final: out = 0.25 * (emb + x1 + x2 + x3)
    combine_kernel<<<(n8 + 255) / 256, 256, 0, stream>>>(embh, x1, x2, x3, out, n8);
}

// Round 8
// 143.003 us; speedup vs baseline: 6.3239x; 1.0689x over previous
//
#include <hip/hip_runtime.h>
#include <math.h>

#define N_NODES 100000
#define DIM 64
#define N_EDGES 1250000
#define SCAN_BLOCKS 256
#define RPB 128                                   // rows per bucket (row>>7)
#define NB_BUCKETS ((N_NODES + RPB - 1) / RPB)    // 782
#define NBLK_B 128                                // blocks in hist/scatter pass
#define CNT_N (NB_BUCKETS * NBLK_B)               // 100096 = 391*256
#define CAP 2048                                  // max edges per bucket (mean 1600)

typedef unsigned short ushort_t;
typedef unsigned int uint_t;
typedef _Float16 h2 __attribute__((ext_vector_type(2)));

// fp16 (storage) <-> f32 (compute) helpers
__device__ __forceinline__ float hlo(uint_t u) {
    return (float)__builtin_bit_cast(_Float16, (ushort_t)(u & 0xFFFFu));
}
__device__ __forceinline__ float hhi(uint_t u) {
    return (float)__builtin_bit_cast(_Float16, (ushort_t)(u >> 16));
}
__device__ __forceinline__ uint_t f2h(float f) {   // RTNE via v_cvt_f16_f32
    return (uint_t)__builtin_bit_cast(ushort_t, (_Float16)f);
}

// acc two fp16 lanes of a dword into two f32 accumulators.
// v_dot2_f32_f16 does the cvt+add in ONE VALU op (products exact: h*1.0).
__device__ __forceinline__ void dacc(float& a0, float& a1, uint_t u) {
#if __has_builtin(__builtin_amdgcn_fdot2)
    h2 h = __builtin_bit_cast(h2, u);
    const h2 e0 = {(_Float16)1.0f, (_Float16)0.0f};
    const h2 e1 = {(_Float16)0.0f, (_Float16)1.0f};
    a0 = __builtin_amdgcn_fdot2(h, e0, a0, false);
    a1 = __builtin_amdgcn_fdot2(h, e1, a1, false);
#else
    a0 += hlo(u);
    a1 += hhi(u);
#endif
}

// ---- fused: blocks [0,NBLK_B) = bucket histogram; rest = emb->fp16 conv ---
__global__ void conv_hist_kernel(const float* __restrict__ emb, ushort_t* __restrict__ embh,
                                 int n8, const int* __restrict__ row,
                                 int* __restrict__ cnt, int E) {
    __shared__ int h[NB_BUCKETS];
    if (blockIdx.x < NBLK_B) {
        for (int i = threadIdx.x; i < NB_BUCKETS; i += blockDim.x) h[i] = 0;
        __syncthreads();
        int blk = blockIdx.x;
        int per = (E + NBLK_B - 1) / NBLK_B;
        int lo = blk * per, hi = min(lo + per, E);
        for (int e = lo + (int)threadIdx.x; e < hi; e += blockDim.x)
            atomicAdd(&h[row[e] >> 7], 1);
        __syncthreads();
        for (int b = threadIdx.x; b < NB_BUCKETS; b += blockDim.x)
            cnt[b * NBLK_B + blk] = h[b];   // bucket-major: scan order = slot order
    } else {
        int i = (blockIdx.x - NBLK_B) * blockDim.x + threadIdx.x;
        if (i < n8) {
            float4 a = reinterpret_cast<const float4*>(emb)[2 * i];
            float4 b = reinterpret_cast<const float4*>(emb)[2 * i + 1];
            uint4 w;
            w.x = f2h(a.x) | (f2h(a.y) << 16);
            w.y = f2h(a.z) | (f2h(a.w) << 16);
            w.z = f2h(b.x) | (f2h(b.y) << 16);
            w.w = f2h(b.z) | (f2h(b.w) << 16);
            reinterpret_cast<uint4*>(embh)[i] = w;
        }
    }
}

// ---- generic 3-kernel device-wide exclusive scan ---------------------------
__global__ void partial_kernel(const int* __restrict__ in, int* __restrict__ blocksum,
                               int N, int chunk) {
    __shared__ int sh[256];
    int b = blockIdx.x;
    int lo = b * chunk, hi = min(lo + chunk, N);
    int s = 0;
    for (int i = lo + (int)threadIdx.x; i < hi; i += 256) s += in[i];
    sh[threadIdx.x] = s;
    __syncthreads();
    for (int off = 128; off > 0; off >>= 1) {
        if ((int)threadIdx.x < off) sh[threadIdx.x] += sh[threadIdx.x + off];
        __syncthreads();
    }
    if (threadIdx.x == 0) blocksum[b] = sh[0];
}

__global__ void scan_small_kernel(int* __restrict__ blocksum, int* __restrict__ out, int N) {
    __shared__ int sh[SCAN_BLOCKS];
    int t = threadIdx.x;
    int v = blocksum[t];
    sh[t] = v;
    __syncthreads();
    for (int off = 1; off < SCAN_BLOCKS; off <<= 1) {
        int u = (t >= off) ? sh[t - off] : 0;
        __syncthreads();
        sh[t] += u;
        __syncthreads();
    }
    blocksum[t] = sh[t] - v;  // exclusive = inclusive - own
    if (t == SCAN_BLOCKS - 1) out[N] = sh[SCAN_BLOCKS - 1];  // total
}

__global__ void scan_emit_kernel(const int* __restrict__ in, const int* __restrict__ blocksum,
                                 int* __restrict__ out, int N, int chunk) {
    __shared__ int sh[256];
    int b = blockIdx.x;
    int t = threadIdx.x;
    int lo = b * chunk, hi = min(lo + chunk, N);
    int running = blocksum[b];
    for (int base = lo; base < hi; base += 256) {
        int i = base + t;
        int d = (i < hi) ? in[i] : 0;
        sh[t] = d;
        __syncthreads();
        for (int off = 1; off < 256; off <<= 1) {
            int u = (t >= off) ? sh[t - off] : 0;
            __syncthreads();
            sh[t] += u;
            __syncthreads();
        }
        if (i < hi) out[i] = running + (sh[t] - d);
        running += sh[255];
        __syncthreads();
    }
}

// ---- bucket pass 2: scatter packed edges into per-(bucket,block) slots ----
__global__ void bucket_scatter_kernel(const int* __restrict__ row, const int* __restrict__ col,
                                      const int* __restrict__ slot_off,
                                      int* __restrict__ pairs, int E) {
    __shared__ int cur[NB_BUCKETS];
    int blk = blockIdx.x;
    for (int b = threadIdx.x; b < NB_BUCKETS; b += blockDim.x)
        cur[b] = slot_off[b * NBLK_B + blk];
    __syncthreads();
    int per = (E + (int)gridDim.x - 1) / (int)gridDim.x;
    int lo = blk * per, hi = min(lo + per, E);
    for (int e = lo + (int)threadIdx.x; e < hi; e += blockDim.x) {
        int r = row[e], c = col[e];
        int pos = atomicAdd(&cur[r >> 7], 1);
        pairs[pos] = ((r & (RPB - 1)) << 17) | c;
    }
}

// ---- bucket pass 3: one block per bucket -> row_ptr, dis, csr (byte offs) --
__global__ void __launch_bounds__(256) bucket_csr_kernel(
        const int* __restrict__ slot_off, const int* __restrict__ pairs,
        int* __restrict__ row_ptr, float* __restrict__ dis,
        int* __restrict__ csr_col, int E) {
    __shared__ int pk[CAP];
    __shared__ int csr_lds[CAP];
    __shared__ int deg_loc[RPB];
    __shared__ int scan_loc[RPB];
    __shared__ int cur_loc[RPB];
    int b = blockIdx.x;
    int t = threadIdx.x;
    int start = slot_off[b * NBLK_B];
    int end = slot_off[(b + 1) * NBLK_B];   // b=NB-1 reads slot_off[CNT_N]=E
    int cnt = end - start;
    bool fits = (cnt <= CAP);

    if (t < RPB) deg_loc[t] = 0;
    if (fits) {
        for (int i = t; i < cnt; i += 256) pk[i] = pairs[start + i];
    }
    __syncthreads();
    for (int i = t; i < cnt; i += 256) {
        int p = fits ? pk[i] : pairs[start + i];
        atomicAdd(&deg_loc[p >> 17], 1);
    }
    __syncthreads();
    int d = (t < RPB) ? deg_loc[t] : 0;
    if (t < RPB) scan_loc[t] = d;
    __syncthreads();
    for (int off = 1; off < RPB; off <<= 1) {
        int v = (t < RPB && t >= off) ? scan_loc[t - off] : 0;
        __syncthreads();
        if (t < RPB) scan_loc[t] += v;
        __syncthreads();
    }
    if (t < RPB) {
        int exc = scan_loc[t] - d;
        cur_loc[t] = exc;
        int rg = b * RPB + t;
        if (rg < N_NODES) {
            row_ptr[rg] = start + exc;
            dis[rg] = (d > 0) ? (float)(1.0 / sqrt((double)d)) : 0.0f;
        }
    }
    __syncthreads();
    // place BYTE OFFSETS (col * DIM * 2 = col<<7) by row within the bucket
    for (int i = t; i < cnt; i += 256) {
        int p = fits ? pk[i] : pairs[start + i];
        int pos = atomicAdd(&cur_loc[p >> 17], 1);
        int c = (p & 0x1FFFF) << 7;
        if (fits) csr_lds[pos] = c;
        else      csr_col[start + pos] = c;
    }
    __syncthreads();
    if (fits) {
        for (int i = t; i < cnt; i += 256) csr_col[start + i] = csr_lds[i];
    }
    if (b == NB_BUCKETS - 1 && t == 0) row_ptr[N_NODES] = E;
}

// Two nodes per wave: lanes 0-31 -> node 2w, lanes 32-63 -> node 2w+1.
// Within a node: 4 groups of 8 lanes; group g handles edges start+g, +4, ...
// Each group loads one full fp16 row (8 lanes x 16B = 128B); accumulate via
// v_dot2_f32_f16 (1 VALU per 2 dims). Cross-group reduce via shfl_xor(8,16).
// MODE 0/1: write x_new = fp16(acc * dis^2)
// MODE 2 (last layer, fused combine): out = 0.25*(embh + x1 + x2 + acc*dis^2)
template <int MODE>
__global__ void gather_kernel(const int* __restrict__ row_ptr, const int* __restrict__ csr_col,
                              const float* __restrict__ dis,
                              const ushort_t* __restrict__ x_old, ushort_t* __restrict__ x_new,
                              const ushort_t* __restrict__ e0, const ushort_t* __restrict__ x1,
                              const ushort_t* __restrict__ x2, float* __restrict__ out,
                              int Npair) {
    int wid = (int)((blockIdx.x * (size_t)blockDim.x + threadIdx.x) >> 6);
    if (wid >= Npair) return;
    int lane = threadIdx.x & 63;
    int sub = lane >> 5;   // which node of the pair
    int l5 = lane & 31;
    int g = l5 >> 3;       // edge-group 0..3 within node
    int l = l5 & 7;        // lane within group: owns dims 8l..8l+7
    int node = wid * 2 + sub;

    int start = row_ptr[node];
    int end = row_ptr[node + 1];

    const char* xb = (const char*)x_old;
    int lb = l * 16;       // lane byte offset within a 128B row

    float acc[8];
    #pragma unroll
    for (int k = 0; k < 8; ++k) acc[k] = 0.f;

    int e = start + g;
    // unroll-by-2 per group: 2 outstanding row loads
    for (; e + 4 < end; e += 8) {
        int o0 = csr_col[e];
        int o1 = csr_col[e + 4];
        uint4 v0 = *reinterpret_cast<const uint4*>(xb + o0 + lb);
        uint4 v1 = *reinterpret_cast<const uint4*>(xb + o1 + lb);
        dacc(acc[0], acc[1], v0.x); dacc(acc[2], acc[3], v0.y);
        dacc(acc[4], acc[5], v0.z); dacc(acc[6], acc[7], v0.w);
        dacc(acc[0], acc[1], v1.x); dacc(acc[2], acc[3], v1.y);
        dacc(acc[4], acc[5], v1.z); dacc(acc[6], acc[7], v1.w);
    }
    if (e < end) {
        int o0 = csr_col[e];
        uint4 v0 = *reinterpret_cast<const uint4*>(xb + o0 + lb);
        dacc(acc[0], acc[1], v0.x); dacc(acc[2], acc[3], v0.y);
        dacc(acc[4], acc[5], v0.z); dacc(acc[6], acc[7], v0.w);
    }

    // sum the 4 groups within this 32-lane half
    #pragma unroll
    for (int off = 8; off <= 16; off <<= 1) {
        #pragma unroll
        for (int k = 0; k < 8; ++k) acc[k] += __shfl_xor(acc[k], off, 64);
    }

    if (g == 0) {
        float s = dis[node];
        float s2 = s * s;
        if (MODE != 2) {
            uint4 w;
            w.x = f2h(acc[0] * s2) | (f2h(acc[1] * s2) << 16);
            w.y = f2h(acc[2] * s2) | (f2h(acc[3] * s2) << 16);
            w.z = f2h(acc[4] * s2) | (f2h(acc[5] * s2) << 16);
            w.w = f2h(acc[6] * s2) | (f2h(acc[7] * s2) << 16);
            *reinterpret_cast<uint4*>(&x_new[(size_t)node * DIM + l * 8]) = w;
        } else {
            // fused combine: out = 0.25 * (embh + x1 + x2 + acc*s2)
            size_t ob = (size_t)node * (DIM * 2) + lb;
            uint4 ea  = *reinterpret_cast<const uint4*>((const char*)e0 + ob);
            uint4 u1  = *reinterpret_cast<const uint4*>((const char*)x1 + ob);
            uint4 u2  = *reinterpret_cast<const uint4*>((const char*)x2 + ob);
            float4 r0, r1;
            r0.x = (hlo(ea.x) + hlo(u1.x) + hlo(u2.x) + acc[0] * s2) * 0.25f;
            r0.y = (hhi(ea.x) + hhi(u1.x) + hhi(u2.x) + acc[1] * s2) * 0.25f;
            r0.z = (hlo(ea.y) + hlo(u1.y) + hlo(u2.y) + acc[2] * s2) * 0.25f;
            r0.w = (hhi(ea.y) + hhi(u1.y) + hhi(u2.y) + acc[3] * s2) * 0.25f;
            r1.x = (hlo(ea.z) + hlo(u1.z) + hlo(u2.z) + acc[4] * s2) * 0.25f;
            r1.y = (hhi(ea.z) + hhi(u1.z) + hhi(u2.z) + acc[5] * s2) * 0.25f;
            r1.z = (hlo(ea.w) + hlo(u1.w) + hlo(u2.w) + acc[6] * s2) * 0.25f;
            r1.w = (hhi(ea.w) + hhi(u1.w) + hhi(u2.w) + acc[7] * s2) * 0.25f;
            size_t oo = (size_t)node * DIM + l * 8;
            *reinterpret_cast<float4*>(&out[oo]) = r0;
            *reinterpret_cast<float4*>(&out[oo + 4]) = r1;
        }
    }
}

extern "C" void kernel_launch(void* const* d_in, const int* in_sizes, int n_in,
                              void* d_out, int out_size, void* d_ws, size_t ws_size,
                              hipStream_t stream) {
    const int* edge = (const int*)d_in[0];       // (2, E) int32
    const int* row = edge;
    const int* col = edge + N_EDGES;
    const float* emb = (const float*)d_in[1];    // (N, 64) f32
    float* out = (float*)d_out;                  // (N, 64) f32

    char* ws = (char*)d_ws;
    size_t off = 0;
    auto alloc = [&](size_t bytes) {
        char* p = ws + off;
        off += (bytes + 255) & ~(size_t)255;
        return p;
    };
    int*      row_ptr  = (int*)alloc(((size_t)N_NODES + 1) * sizeof(int));
    float*    dis      = (float*)alloc((size_t)N_NODES * sizeof(float));
    int*      blocksum = (int*)alloc((size_t)SCAN_BLOCKS * sizeof(int));
    int*      cnt      = (int*)alloc((size_t)CNT_N * sizeof(int));
    int*      slot_off = (int*)alloc(((size_t)CNT_N + 1) * sizeof(int));
    int*      csr_col  = (int*)alloc((size_t)N_EDGES * sizeof(int));
    ushort_t* embh     = (ushort_t*)alloc((size_t)N_NODES * DIM * sizeof(ushort_t));
    ushort_t* x1       = (ushort_t*)alloc((size_t)N_NODES * DIM * sizeof(ushort_t));
    ushort_t* x2       = (ushort_t*)alloc((size_t)N_NODES * DIM * sizeof(ushort_t));
    // pairs (5MB) aliases x2 (12.8MB): pairs dead after bucket_csr_kernel,
    // x2 first written by the second gather (later) -> lifetimes disjoint.
    int*      pairs    = (int*)x2;

    const int gather_blocks = (N_NODES / 2 * 64) / 256;   // 2 nodes per wave
    const int chunk = (CNT_N + SCAN_BLOCKS - 1) / SCAN_BLOCKS;
    const int n8 = N_NODES * DIM / 8;

    // CSR build via 2-level bucket sort; conv fused with hist
    conv_hist_kernel<<<NBLK_B + (n8 + 255) / 256, 256, 0, stream>>>(emb, embh, n8, row, cnt, N_EDGES);
    partial_kernel<<<SCAN_BLOCKS, 256, 0, stream>>>(cnt, blocksum, CNT_N, chunk);
    scan_small_kernel<<<1, SCAN_BLOCKS, 0, stream>>>(blocksum, slot_off, CNT_N);
    scan_emit_kernel<<<SCAN_BLOCKS, 256, 0, stream>>>(cnt, blocksum, slot_off, CNT_N, chunk);
    bucket_scatter_kernel<<<NBLK_B, 256, 0, stream>>>(row, col, slot_off, pairs, N_EDGES);
    bucket_csr_kernel<<<NB_BUCKETS, 256, 0, stream>>>(slot_off, pairs, row_ptr, dis, csr_col, N_EDGES);

    // 3 propagate layers (fp16 storage, f32 accumulate via v_dot2_f32_f16);
    // layer 3 fuses the final combine: out = 0.25*(emb + x1 + x2 + x3)
    gather_kernel<0><<<gather_blocks, 256, 0, stream>>>(row_ptr, csr_col, dis, embh, x1,
                                                        nullptr, nullptr, nullptr, nullptr, N_NODES / 2);
    gather_kernel<1><<<gather_blocks, 256, 0, stream>>>(row_ptr, csr_col, dis, x1, x2,
                                                        nullptr, nullptr, nullptr, nullptr, N_NODES / 2);
    gather_kernel<2><<<gather_blocks, 256, 0, stream>>>(row_ptr, csr_col, dis, x2, nullptr,
                                                        embh, x1, x2, out, N_NODES / 2);
}